// Round 7
// baseline (481.617 us; speedup 1.0000x reference)
//
#include <hip/hip_runtime.h>
#include <hip/hip_bf16.h>

#define HID 128
#define NRAW 127
#define EW 2048        // LDS-staged csr window (edges), fits in Cs union (8 KB)

// Column permutation: all hidden-state tensors (h8a/h8b, hg) store logical
// column l = ot*16+m at physical position p = m*8+ot; inverse invp(p) = (p&7)*16+(p>>3).
// GEMM weights and the first Wc1 application are k-permuted to match.
//
// CSR: per-node atomic count -> 3-stage hierarchical scan -> direct atomic
// placement (no bucket sort, no staging buffer). Edge order within a node is
// nondeterministic; sums are fp32-commutative and the col0 deg-sum is exact.
//
// Aggregation (R5 champion): 8-lane group per node, lane owns a 16B uint4 chunk
// of the node's 128B fp8 row; one gather covers 8 rows; unroll-4; indices from
// an LDS-staged window; 32 nodes/block; A-tile XOR-swizzled.
// Layer 3 fuses the graph mean-pool into its epilogue (reads Cs from LDS).

typedef __attribute__((ext_vector_type(8))) short short8;
typedef __attribute__((ext_vector_type(4))) float floatx4;
typedef __attribute__((ext_vector_type(2))) float floatx2;

__device__ inline unsigned pack_bf2(float x, float y) {
    unsigned bx = __float_as_uint(x);
    unsigned by = __float_as_uint(y);
    bx += 0x7fffu + ((bx >> 16) & 1u);   // RNE
    by += 0x7fffu + ((by >> 16) & 1u);
    return (bx >> 16) | (by & 0xffff0000u);
}
__device__ inline float bf_lo(unsigned u) { return __uint_as_float(u << 16); }
__device__ inline float bf_hi(unsigned u) { return __uint_as_float(u & 0xffff0000u); }

// ---------------- init: zeros + permuted weight packs + sentinel rows ----------------

__global__ __launch_bounds__(256) void init_kernel(const float* __restrict__ W0,
                            const float* __restrict__ W1,
                            const float* __restrict__ W2, const float* __restrict__ Wc1,
                            unsigned* __restrict__ O0, unsigned* __restrict__ O1,
                            unsigned* __restrict__ O2, float* __restrict__ Wc1p,
                            int* __restrict__ degc, float* __restrict__ hg,
                            float* __restrict__ counts, float* __restrict__ degf,
                            unsigned* __restrict__ h8a, unsigned* __restrict__ h8b,
                            int G, int N) {
    int id = blockIdx.x * blockDim.x + threadIdx.x;
    if (id < N) degc[id] = 0;
    if (id < G * HID) hg[id] = 0.f;
    if (id < G) counts[id] = 0.f;
    if (id == 0) degf[N] = 0.f;          // sentinel degree
    if (id < 32) {                       // sentinel zero rows (safety)
        h8a[(size_t)N * 32 + id] = 0u;
        h8b[(size_t)N * 32 + id] = 0u;
    }
    if (id < 16384) {   // Wc1 with permuted k for the first head matmul
        int t = id >> 7, p = id & 127;
        Wc1p[id] = Wc1[t * 128 + ((p & 7) * 16 + (p >> 3))];
    }
    if (id < 3 * 8192) {   // GCN weights, bf16, k-permuted
        int sel = id >> 13, l = id & 8191;
        const float* W = sel == 0 ? W0 : (sel == 1 ? W1 : W2);
        unsigned* O = sel == 0 ? O0 : (sel == 1 ? O1 : O2);
        int o = l >> 6, pp = (l & 63) * 2;
        int k0 = (pp & 7) * 16 + (pp >> 3);
        int k1 = ((pp + 1) & 7) * 16 + ((pp + 1) >> 3);
        O[l] = pack_bf2(W[o * 128 + k0], W[o * 128 + k1]);
    }
}

// ---------------- CSR build: atomic count -> scan -> atomic placement ----------------

__global__ __launch_bounds__(256) void deg_count_kernel(const int* __restrict__ dst,
                                                        int* __restrict__ degc, int E) {
    int base = blockIdx.x * 4096 + threadIdx.x;
    #pragma unroll
    for (int j = 0; j < 16; ++j) {
        int e = base + j * 256;
        if (e < E) atomicAdd(&degc[dst[e]], 1);
    }
}

__global__ __launch_bounds__(1024) void scan1_kernel(const int* __restrict__ degc,
                                                     int* __restrict__ rp,
                                                     float* __restrict__ degf,
                                                     int* __restrict__ bsum, int N) {
    __shared__ int sm[1024];
    int t = threadIdx.x, j = blockIdx.x * 1024 + t;
    int v = (j < N) ? degc[j] : 0;
    if (j < N) degf[j] = (float)v;
    sm[t] = v;
    __syncthreads();
    for (int off = 1; off < 1024; off <<= 1) {
        int add = (t >= off) ? sm[t - off] : 0;
        __syncthreads();
        sm[t] += add;
        __syncthreads();
    }
    if (j <= N) rp[j] = sm[t] - v;       // exclusive, block-local
    if (t == 1023) bsum[blockIdx.x] = sm[1023];
}

__global__ void scan2_kernel(int* __restrict__ bsum, int NS) {   // NS <= 128
    __shared__ int sm[128];
    int t = threadIdx.x;
    int v = (t < NS) ? bsum[t] : 0;
    sm[t] = v;
    __syncthreads();
    for (int off = 1; off < 128; off <<= 1) {
        int add = (t >= off) ? sm[t - off] : 0;
        __syncthreads();
        sm[t] += add;
        __syncthreads();
    }
    if (t < NS) bsum[t] = sm[t] - v;     // exclusive block offsets
}

__global__ __launch_bounds__(1024) void scan3_kernel(int* __restrict__ rp,
                                                     const int* __restrict__ bsum, int N) {
    int j = blockIdx.x * 1024 + threadIdx.x;
    if (j <= N) rp[j] += bsum[blockIdx.x];
}

// pos = rp[d] + (atomicSub(degc[d]) - 1): fills each node's range backwards.
__global__ __launch_bounds__(256) void scatter_kernel(const int* __restrict__ src,
                                                      const int* __restrict__ dst,
                                                      int* __restrict__ degc,
                                                      const int* __restrict__ rp,
                                                      int* __restrict__ csr, int E) {
    int base = blockIdx.x * 4096 + threadIdx.x;
    #pragma unroll
    for (int j = 0; j < 16; ++j) {
        int e = base + j * 256;
        if (e < E) {
            int d = dst[e];
            int o = atomicSub(&degc[d], 1);
            csr[rp[d] + o - 1] = src[e];
        }
    }
}

// ---------------- h0 in fp8, permuted layout, coalesced via LDS row staging ----------------

__global__ __launch_bounds__(256) void build_h0_kernel(const float* __restrict__ feat,
                                                       unsigned* __restrict__ h8, int N) {
    __shared__ float lf[8 * NRAW];
    int t = threadIdx.x;
    int n0 = blockIdx.x * 8;
    int nrows = min(8, N - n0);
    int total = nrows * NRAW;
    for (int j = t; j < total; j += 256) lf[j] = feat[(size_t)n0 * NRAW + j];
    __syncthreads();
    int n = t >> 5, c = t & 31;
    if (n < nrows) {
        const float* fr = lf + n * NRAW;
        int base = c >> 1, hb = (c & 1) * 4;
        float f[4];
        #pragma unroll
        for (int j = 0; j < 4; ++j) {
            int l = (hb + j) * 16 + base;   // logical col at physical byte 4c+j
            f[j] = (l == 0) ? 0.f : fr[l - 1];
        }
        unsigned w = __builtin_amdgcn_cvt_pk_fp8_f32(f[0], f[1], 0, false);
        w = __builtin_amdgcn_cvt_pk_fp8_f32(f[2], f[3], w, true);
        h8[(size_t)(n0 + n) * 32 + c] = w;
    }
}

// ---------------- fused GCN layer: 8-lane-group agg -> LDS A-tile -> MFMA ----------------
// 32 nodes per 256-thread block. Lane = (group grp = lane>>3 -> node, chunk cc4 =
// lane&7 -> 16B uint4 of the row). One gather instruction covers 8 node rows.
// Unroll-4 over edges. sIdx window UNIONED with Cs (disjoint phases) -> 16 KB LDS.
// dopool: layer-3 epilogue pools Cs (bf16) into hg/counts via atomics (no hB).

__global__ __launch_bounds__(256, 4) void gcn_fused_kernel(const unsigned* __restrict__ h8,
                                                           unsigned* __restrict__ out8,
                                                           const unsigned* __restrict__ Wb,
                                                           const float* __restrict__ bias,
                                                           const int* __restrict__ rp,
                                                           const int* __restrict__ csr,
                                                           const float* __restrict__ degf,
                                                           const int* __restrict__ gid,
                                                           float* __restrict__ hgp,
                                                           float* __restrict__ cntp,
                                                           int col0fix, int dopool, int N) {
    __shared__ unsigned Al[32 * 64];     // A tile, swizzled: row r granule gr at Al[(r*16 + (gr^(r&7)))*4]
    __shared__ unsigned CsS[32 * 64];    // C staging; first EW*4 bytes double as sIdx during agg
    int* sIdx = (int*)CsS;
    int t = threadIdx.x;
    int wv = t >> 6, lane = t & 63;
    int grp = lane >> 3;               // node group 0..7 within wave
    int cc4 = lane & 7;                // 16B chunk 0..7
    int n0 = blockIdx.x * 32;
    int g32 = wv * 8 + grp;            // local row 0..31
    int i = n0 + g32;
    const char* hbase = (const char*)h8;
    unsigned c16 = (unsigned)cc4 * 16u;

    int start = 0, end = 0;
    if (i < N) { start = rp[i]; end = rp[i + 1]; }
    int deg = end - start;
    int nEnd = min(n0 + 32, N);
    int s0 = rp[n0];                   // block-uniform
    int e1 = rp[nEnd];

    floatx2 a0 = {0.f, 0.f}, a1 = {0.f, 0.f}, a2 = {0.f, 0.f}, a3 = {0.f, 0.f};
    floatx2 a4 = {0.f, 0.f}, a5 = {0.f, 0.f}, a6 = {0.f, 0.f}, a7 = {0.f, 0.f};
    float dsum = 0.f;

    #define GATH4(ii) (*(const uint4*)(hbase + (((unsigned)(ii) << 7) + c16)))
    #define ACC4(vv) do { \
        a0 += __builtin_amdgcn_cvt_pk_f32_fp8((vv).x, false); \
        a1 += __builtin_amdgcn_cvt_pk_f32_fp8((vv).x, true);  \
        a2 += __builtin_amdgcn_cvt_pk_f32_fp8((vv).y, false); \
        a3 += __builtin_amdgcn_cvt_pk_f32_fp8((vv).y, true);  \
        a4 += __builtin_amdgcn_cvt_pk_f32_fp8((vv).z, false); \
        a5 += __builtin_amdgcn_cvt_pk_f32_fp8((vv).z, true);  \
        a6 += __builtin_amdgcn_cvt_pk_f32_fp8((vv).w, false); \
        a7 += __builtin_amdgcn_cvt_pk_f32_fp8((vv).w, true);  \
    } while (0)

    for (int w0 = s0; w0 < e1; w0 += EW) {
        if (w0 > s0) __syncthreads();   // protect sIdx reuse (uniform cond)
        int wcnt = min(EW, e1 - w0);
        for (int j = t; j < wcnt; j += 256) sIdx[j] = csr[w0 + j];
        __syncthreads();
        int p  = max(start, w0) - w0;
        int pe = min(end, w0 + wcnt) - w0;
        for (; p + 4 <= pe; p += 4) {
            int iA = sIdx[p], iB = sIdx[p + 1], iC = sIdx[p + 2], iD = sIdx[p + 3];
            uint4 vA = GATH4(iA), vB = GATH4(iB), vC = GATH4(iC), vD = GATH4(iD);
            if (col0fix && cc4 == 0)
                dsum += degf[iA] + degf[iB] + degf[iC] + degf[iD];
            ACC4(vA); ACC4(vB); ACC4(vC); ACC4(vD);
        }
        for (; p + 2 <= pe; p += 2) {
            int iA = sIdx[p], iB = sIdx[p + 1];
            uint4 vA = GATH4(iA), vB = GATH4(iB);
            if (col0fix && cc4 == 0) dsum += degf[iA] + degf[iB];
            ACC4(vA); ACC4(vB);
        }
        for (; p < pe; ++p) {
            int iA = sIdx[p];
            uint4 vA = GATH4(iA);
            if (col0fix && cc4 == 0) dsum += degf[iA];
            ACC4(vA);
        }
    }

    if (i < N) {
        float inv;
        if (deg == 0) {                 // keep old h: accumulate own row once
            uint4 v = GATH4(i);
            ACC4(v);
            inv = 1.f;
        } else {
            if (col0fix && cc4 == 0) a0[0] = dsum;   // exact neighbor-deg sum -> logical col 0
            inv = 1.f / (float)deg;
        }
        uint4 r0, r1;
        r0.x = pack_bf2(a0[0] * inv, a0[1] * inv);
        r0.y = pack_bf2(a1[0] * inv, a1[1] * inv);
        r0.z = pack_bf2(a2[0] * inv, a2[1] * inv);
        r0.w = pack_bf2(a3[0] * inv, a3[1] * inv);
        r1.x = pack_bf2(a4[0] * inv, a4[1] * inv);
        r1.y = pack_bf2(a5[0] * inv, a5[1] * inv);
        r1.z = pack_bf2(a6[0] * inv, a6[1] * inv);
        r1.w = pack_bf2(a7[0] * inv, a7[1] * inv);
        int gr0 = 2 * cc4, gr1 = 2 * cc4 + 1;
        *(uint4*)&Al[(g32 * 16 + (gr0 ^ (g32 & 7))) * 4] = r0;
        *(uint4*)&Al[(g32 * 16 + (gr1 ^ (g32 & 7))) * 4] = r1;
    }
    __syncthreads();

    // ---- GEMM phase: wave wv -> rows rh*16..+15, output tiles ot=cq*4..cq*4+3 ----
    {
        int rh = wv & 1, cq = wv >> 1;
        int m = lane & 15, q = lane >> 4;
        int r = rh * 16 + m;           // A row (node) index
        floatx4 acc0 = (floatx4)(0.f), acc1 = (floatx4)(0.f);
        floatx4 acc2 = (floatx4)(0.f), acc3 = (floatx4)(0.f);
        #pragma unroll
        for (int kt = 0; kt < 4; ++kt) {
            short8 af = *(const short8*)&Al[(r * 16 + ((kt * 4 + q) ^ (m & 7))) * 4];
            short8 b0 = *(const short8*)&Wb[((cq * 4 + 0) * 16 + m) * 64 + kt * 16 + q * 4];
            short8 b1 = *(const short8*)&Wb[((cq * 4 + 1) * 16 + m) * 64 + kt * 16 + q * 4];
            short8 b2 = *(const short8*)&Wb[((cq * 4 + 2) * 16 + m) * 64 + kt * 16 + q * 4];
            short8 b3 = *(const short8*)&Wb[((cq * 4 + 3) * 16 + m) * 64 + kt * 16 + q * 4];
            acc0 = __builtin_amdgcn_mfma_f32_16x16x32_bf16(af, b0, acc0, 0, 0, 0);
            acc1 = __builtin_amdgcn_mfma_f32_16x16x32_bf16(af, b1, acc1, 0, 0, 0);
            acc2 = __builtin_amdgcn_mfma_f32_16x16x32_bf16(af, b2, acc2, 0, 0, 0);
            acc3 = __builtin_amdgcn_mfma_f32_16x16x32_bf16(af, b3, acc3, 0, 0, 0);
        }
        float bv0 = bias[(cq * 4 + 0) * 16 + m];
        float bv1 = bias[(cq * 4 + 1) * 16 + m];
        float bv2 = bias[(cq * 4 + 2) * 16 + m];
        float bv3 = bias[(cq * 4 + 3) * 16 + m];
        #pragma unroll
        for (int r4 = 0; r4 < 4; ++r4) {
            int row = rh * 16 + q * 4 + r4;
            float v0 = fmaxf(acc0[r4] + bv0, 0.f);
            float v1 = fmaxf(acc1[r4] + bv1, 0.f);
            float v2 = fmaxf(acc2[r4] + bv2, 0.f);
            float v3 = fmaxf(acc3[r4] + bv3, 0.f);
            if (out8) {
                // phys fp8 bytes m*8 + cq*4 + {0..3} -> one aligned u32
                unsigned pk = __builtin_amdgcn_cvt_pk_fp8_f32(v0, v1, 0, false);
                pk = __builtin_amdgcn_cvt_pk_fp8_f32(v2, v3, pk, true);
                *(unsigned*)((char*)CsS + row * 128 + m * 8 + cq * 4) = pk;
            } else {
                // phys bf16 u32 indices m*4 + cq*2 + {0,1} within row of 64 u32
                CsS[row * 64 + m * 4 + cq * 2 + 0] = pack_bf2(v0, v1);
                CsS[row * 64 + m * 4 + cq * 2 + 1] = pack_bf2(v2, v3);
            }
        }
    }
    __syncthreads();

    // ---- epilogue: fp8 writeout (layers 0,1) or fused graph mean-pool (layer 2) ----
    if (dopool) {
        int q = t >> 6, c = t & 63;
        float ax = 0.f, ay = 0.f, cnt = 0.f;
        int cur = -1;
        for (int n = q; n < 32; n += 4) {
            int nd = n0 + n;
            if (nd >= N) break;
            int g = gid[nd];
            if (g != cur) {
                if (cur >= 0) {
                    atomicAdd(&hgp[cur * HID + 2 * c], ax);
                    atomicAdd(&hgp[cur * HID + 2 * c + 1], ay);
                    if (c == 0) atomicAdd(&cntp[cur], cnt);
                }
                ax = ay = cnt = 0.f;
                cur = g;
            }
            unsigned v = CsS[n * 64 + c];
            ax += bf_lo(v); ay += bf_hi(v);
            cnt += 1.f;
        }
        if (cur >= 0) {
            atomicAdd(&hgp[cur * HID + 2 * c], ax);
            atomicAdd(&hgp[cur * HID + 2 * c + 1], ay);
            if (c == 0) atomicAdd(&cntp[cur], cnt);
        }
    } else {
        int row = t >> 3, gg = t & 7;
        int n = n0 + row;
        if (n < N) {
            ((uint4*)out8)[(size_t)n * 8 + gg] =
                *(const uint4*)((const char*)CsS + row * 128 + gg * 16);
        }
    }
    #undef GATH4
    #undef ACC4
}

// ---------------- fused classifier head (fp32), one block per graph ----------------

__global__ __launch_bounds__(128) void cls_fused_kernel(const float* __restrict__ hg,
                                                        const float* __restrict__ counts,
                                                        const float* __restrict__ Wc1p,
                                                        const float* __restrict__ Wc1,
                                                        const float* __restrict__ bc1,
                                                        const float* __restrict__ Wc2,
                                                        const float* __restrict__ bc2,
                                                        float* __restrict__ out, int G) {
    __shared__ float x[128];
    __shared__ float y[128];
    __shared__ float red[128];
    int g = blockIdx.x, t = threadIdx.x;
    float inv = 1.f / fmaxf(counts[g], 1.f);
    x[t] = hg[g * HID + t] * inv;
    __syncthreads();
    const float4* wp4 = (const float4*)(Wc1p + t * HID);
    float s = 0.f;
    #pragma unroll
    for (int k4 = 0; k4 < 32; ++k4) {
        float4 w = wp4[k4];
        s += x[k4 * 4] * w.x + x[k4 * 4 + 1] * w.y + x[k4 * 4 + 2] * w.z + x[k4 * 4 + 3] * w.w;
    }
    y[t] = s + bc1[t];
    __syncthreads();
    const float4* w4 = (const float4*)(Wc1 + t * HID);
    float s2 = 0.f;
    #pragma unroll
    for (int k4 = 0; k4 < 32; ++k4) {
        float4 w = w4[k4];
        s2 += y[k4 * 4] * w.x + y[k4 * 4 + 1] * w.y + y[k4 * 4 + 2] * w.z + y[k4 * 4 + 3] * w.w;
    }
    red[t] = (s2 + bc1[t]) * Wc2[t];
    __syncthreads();
    if (t < 64) {
        float r = red[t] + red[t + 64];
        #pragma unroll
        for (int off = 32; off > 0; off >>= 1) r += __shfl_down(r, off);
        if (t == 0) out[g] = r + bc2[0];
    }
}

// ---------------- launch ----------------

extern "C" void kernel_launch(void* const* d_in, const int* in_sizes, int n_in,
                              void* d_out, int out_size, void* d_ws, size_t ws_size,
                              hipStream_t stream) {
    const float* feat = (const float*)d_in[0];
    const int* src    = (const int*)d_in[1];
    const int* dst    = (const int*)d_in[2];
    const int* gid    = (const int*)d_in[3];
    const float* W0  = (const float*)d_in[5];
    const float* b0  = (const float*)d_in[6];
    const float* W1  = (const float*)d_in[7];
    const float* b1  = (const float*)d_in[8];
    const float* W2  = (const float*)d_in[9];
    const float* b2  = (const float*)d_in[10];
    const float* Wc1 = (const float*)d_in[11];
    const float* bc1 = (const float*)d_in[12];
    const float* Wc2 = (const float*)d_in[13];
    const float* bc2 = (const float*)d_in[14];

    const int N = in_sizes[3];
    const int E = in_sizes[1];
    const int G = out_size;

    char* ws = (char*)d_ws;
    size_t off = 0;
    auto alloc = [&](size_t bytes) { void* p = ws + off; off += (bytes + 255) & ~size_t(255); return p; };
    unsigned* h8a    = (unsigned*)alloc((size_t)(N + 1) * 32 * 4);   // fp8 h buffer A (+sentinel row)
    unsigned* h8b    = (unsigned*)alloc((size_t)(N + 1) * 32 * 4);   // fp8 h buffer B (+sentinel row)
    float* degf      = (float*)alloc((size_t)(N + 1) * 4);           // exact in-degree (+sentinel 0)
    int* degc        = (int*)alloc((size_t)N * 4);                   // atomic deg counters / cursors
    int* csr         = (int*)alloc((size_t)(E + 64) * 4);
    int* rp          = (int*)alloc((size_t)(N + 1) * 4);
    int* bsum        = (int*)alloc(512 * 4);
    unsigned* Wb0    = (unsigned*)alloc(8192 * 4);
    unsigned* Wb1    = (unsigned*)alloc(8192 * 4);
    unsigned* Wb2    = (unsigned*)alloc(8192 * 4);
    float* Wc1p      = (float*)alloc(16384 * 4);
    float* hg        = (float*)alloc((size_t)G * HID * 4);
    float* counts    = (float*)alloc((size_t)G * 4);

    int initg = (N + 255) / 256;
    init_kernel<<<initg, 256, 0, stream>>>(W0, W1, W2, Wc1, Wb0, Wb1, Wb2, Wc1p,
                                           degc, hg, counts, degf, h8a, h8b, G, N);

    int gE = (E + 4095) / 4096;
    int NS = (N + 1 + 1023) / 1024;      // scan blocks (<=128)
    deg_count_kernel<<<gE, 256, 0, stream>>>(dst, degc, E);
    scan1_kernel<<<NS, 1024, 0, stream>>>(degc, rp, degf, bsum, N);
    scan2_kernel<<<1, 128, 0, stream>>>(bsum, NS);
    scan3_kernel<<<NS, 1024, 0, stream>>>(rp, bsum, N);
    scatter_kernel<<<gE, 256, 0, stream>>>(src, dst, degc, rp, csr, E);

    build_h0_kernel<<<(N + 7) / 8, 256, 0, stream>>>(feat, h8a, N);

    int layer_grid = (N + 31) / 32;
    gcn_fused_kernel<<<layer_grid, 256, 0, stream>>>(h8a, h8b, Wb0, b0, rp, csr, degf,
                                                     nullptr, nullptr, nullptr, 1, 0, N);
    gcn_fused_kernel<<<layer_grid, 256, 0, stream>>>(h8b, h8a, Wb1, b1, rp, csr, degf,
                                                     nullptr, nullptr, nullptr, 0, 0, N);
    gcn_fused_kernel<<<layer_grid, 256, 0, stream>>>(h8a, nullptr, Wb2, b2, rp, csr, degf,
                                                     gid, hg, counts, 0, 1, N);

    cls_fused_kernel<<<G, 128, 0, stream>>>(hg, counts, Wc1p, Wc1, bc1, Wc2, bc2,
                                            (float*)d_out, G);
}

// Round 8
// 458.683 us; speedup vs baseline: 1.0500x; 1.0500x over previous
//
#include <hip/hip_runtime.h>
#include <hip/hip_bf16.h>

#define HID 128
#define NRAW 127
#define EW 2048        // LDS-staged csr window (edges), fits in Cs union (8 KB)

// Column permutation: all hidden-state tensors (h8a/h8b, hB, hg) store logical
// column l = ot*16+m at physical position p = m*8+ot; inverse invp(p) = (p&7)*16+(p>>3).
// GEMM weights and the first Wc1 application are k-permuted to match.
//
// CSR: per-node atomic count -> 3-stage scan -> forward atomic placement
// (cur[] cursor => within-node order ~ ascending edge index, like the old
// bucket sort). rp/degf are value-identical to the bucketed builder.
//
// gcn_fused_kernel / pool_kernel / build_h0 / cls are byte-for-byte the
// 356-us champion (R5): the dopool-branch variant perturbed the compiler's
// vmcnt placement in the agg loop and halved gather pipelining (R7 post-mortem).

typedef __attribute__((ext_vector_type(8))) short short8;
typedef __attribute__((ext_vector_type(4))) float floatx4;
typedef __attribute__((ext_vector_type(2))) float floatx2;

__device__ inline unsigned pack_bf2(float x, float y) {
    unsigned bx = __float_as_uint(x);
    unsigned by = __float_as_uint(y);
    bx += 0x7fffu + ((bx >> 16) & 1u);   // RNE
    by += 0x7fffu + ((by >> 16) & 1u);
    return (bx >> 16) | (by & 0xffff0000u);
}
__device__ inline float bf_lo(unsigned u) { return __uint_as_float(u << 16); }
__device__ inline float bf_hi(unsigned u) { return __uint_as_float(u & 0xffff0000u); }

// ---------------- init: zeros + permuted weight packs + sentinel rows ----------------

__global__ __launch_bounds__(256) void init_kernel(const float* __restrict__ W0,
                            const float* __restrict__ W1,
                            const float* __restrict__ W2, const float* __restrict__ Wc1,
                            unsigned* __restrict__ O0, unsigned* __restrict__ O1,
                            unsigned* __restrict__ O2, float* __restrict__ Wc1p,
                            int* __restrict__ degc, int* __restrict__ cur,
                            float* __restrict__ hg,
                            float* __restrict__ counts, float* __restrict__ degf,
                            unsigned* __restrict__ h8a, unsigned* __restrict__ h8b,
                            int G, int N) {
    int id = blockIdx.x * blockDim.x + threadIdx.x;
    if (id < N) { degc[id] = 0; cur[id] = 0; }
    if (id < G * HID) hg[id] = 0.f;
    if (id < G) counts[id] = 0.f;
    if (id == 0) degf[N] = 0.f;          // sentinel degree
    if (id < 32) {                       // sentinel zero rows (safety)
        h8a[(size_t)N * 32 + id] = 0u;
        h8b[(size_t)N * 32 + id] = 0u;
    }
    if (id < 16384) {   // Wc1 with permuted k for the first head matmul
        int t = id >> 7, p = id & 127;
        Wc1p[id] = Wc1[t * 128 + ((p & 7) * 16 + (p >> 3))];
    }
    if (id < 3 * 8192) {   // GCN weights, bf16, k-permuted
        int sel = id >> 13, l = id & 8191;
        const float* W = sel == 0 ? W0 : (sel == 1 ? W1 : W2);
        unsigned* O = sel == 0 ? O0 : (sel == 1 ? O1 : O2);
        int o = l >> 6, pp = (l & 63) * 2;
        int k0 = (pp & 7) * 16 + (pp >> 3);
        int k1 = ((pp + 1) & 7) * 16 + ((pp + 1) >> 3);
        O[l] = pack_bf2(W[o * 128 + k0], W[o * 128 + k1]);
    }
}

// ---------------- CSR build: atomic count -> scan -> forward atomic placement ----------------

__global__ __launch_bounds__(256) void deg_count_kernel(const int* __restrict__ dst,
                                                        int* __restrict__ degc, int E) {
    int base = blockIdx.x * 4096 + threadIdx.x;
    #pragma unroll
    for (int j = 0; j < 16; ++j) {
        int e = base + j * 256;
        if (e < E) atomicAdd(&degc[dst[e]], 1);
    }
}

__global__ __launch_bounds__(1024) void scan1_kernel(const int* __restrict__ degc,
                                                     int* __restrict__ rp,
                                                     float* __restrict__ degf,
                                                     int* __restrict__ bsum, int N) {
    __shared__ int sm[1024];
    int t = threadIdx.x, j = blockIdx.x * 1024 + t;
    int v = (j < N) ? degc[j] : 0;
    if (j < N) degf[j] = (float)v;
    sm[t] = v;
    __syncthreads();
    for (int off = 1; off < 1024; off <<= 1) {
        int add = (t >= off) ? sm[t - off] : 0;
        __syncthreads();
        sm[t] += add;
        __syncthreads();
    }
    if (j <= N) rp[j] = sm[t] - v;       // exclusive, block-local
    if (t == 1023) bsum[blockIdx.x] = sm[1023];
}

__global__ void scan2_kernel(int* __restrict__ bsum, int NS) {   // NS <= 128
    __shared__ int sm[128];
    int t = threadIdx.x;
    int v = (t < NS) ? bsum[t] : 0;
    sm[t] = v;
    __syncthreads();
    for (int off = 1; off < 128; off <<= 1) {
        int add = (t >= off) ? sm[t - off] : 0;
        __syncthreads();
        sm[t] += add;
        __syncthreads();
    }
    if (t < NS) bsum[t] = sm[t] - v;     // exclusive block offsets
}

__global__ __launch_bounds__(1024) void scan3_kernel(int* __restrict__ rp,
                                                     const int* __restrict__ bsum, int N) {
    int j = blockIdx.x * 1024 + threadIdx.x;
    if (j <= N) rp[j] += bsum[blockIdx.x];
}

// forward placement: pos = rp[d] + atomicAdd(cur[d], 1)
__global__ __launch_bounds__(256) void scatter_kernel(const int* __restrict__ src,
                                                      const int* __restrict__ dst,
                                                      int* __restrict__ cur,
                                                      const int* __restrict__ rp,
                                                      int* __restrict__ csr, int E) {
    int base = blockIdx.x * 4096 + threadIdx.x;
    #pragma unroll
    for (int j = 0; j < 16; ++j) {
        int e = base + j * 256;
        if (e < E) {
            int d = dst[e];
            int o = atomicAdd(&cur[d], 1);
            csr[rp[d] + o] = src[e];
        }
    }
}

// ---------------- h0 in fp8, permuted layout, coalesced via LDS row staging ----------------

__global__ __launch_bounds__(256) void build_h0_kernel(const float* __restrict__ feat,
                                                       unsigned* __restrict__ h8, int N) {
    __shared__ float lf[8 * NRAW];
    int t = threadIdx.x;
    int n0 = blockIdx.x * 8;
    int nrows = min(8, N - n0);
    int total = nrows * NRAW;
    for (int j = t; j < total; j += 256) lf[j] = feat[(size_t)n0 * NRAW + j];
    __syncthreads();
    int n = t >> 5, c = t & 31;
    if (n < nrows) {
        const float* fr = lf + n * NRAW;
        int base = c >> 1, hb = (c & 1) * 4;
        float f[4];
        #pragma unroll
        for (int j = 0; j < 4; ++j) {
            int l = (hb + j) * 16 + base;   // logical col at physical byte 4c+j
            f[j] = (l == 0) ? 0.f : fr[l - 1];
        }
        unsigned w = __builtin_amdgcn_cvt_pk_fp8_f32(f[0], f[1], 0, false);
        w = __builtin_amdgcn_cvt_pk_fp8_f32(f[2], f[3], w, true);
        h8[(size_t)(n0 + n) * 32 + c] = w;
    }
}

// ---------------- fused GCN layer: 8-lane-group agg -> LDS A-tile -> MFMA ----------------
// (byte-for-byte the 356-us champion kernel)
// 32 nodes per 256-thread block. Lane = (group grp = lane>>3 -> node, chunk cc4 =
// lane&7 -> 16B uint4 of the row). One gather instruction covers 8 node rows.
// Unroll-4 over edges. sIdx window UNIONED with Cs (disjoint phases) -> 16 KB LDS.

__global__ __launch_bounds__(256, 4) void gcn_fused_kernel(const unsigned* __restrict__ h8,
                                                           unsigned* __restrict__ out8,
                                                           unsigned* __restrict__ outb,
                                                           const unsigned* __restrict__ Wb,
                                                           const float* __restrict__ bias,
                                                           const int* __restrict__ rp,
                                                           const int* __restrict__ csr,
                                                           const float* __restrict__ degf,
                                                           int col0fix, int N) {
    __shared__ unsigned Al[32 * 64];     // A tile, swizzled: row r granule gr at Al[(r*16 + (gr^(r&7)))*4]
    __shared__ unsigned CsS[32 * 64];    // C staging; first EW*4 bytes double as sIdx during agg
    int* sIdx = (int*)CsS;
    int t = threadIdx.x;
    int wv = t >> 6, lane = t & 63;
    int grp = lane >> 3;               // node group 0..7 within wave
    int cc4 = lane & 7;                // 16B chunk 0..7
    int n0 = blockIdx.x * 32;
    int g32 = wv * 8 + grp;            // local row 0..31
    int i = n0 + g32;
    const char* hbase = (const char*)h8;
    unsigned c16 = (unsigned)cc4 * 16u;

    int start = 0, end = 0;
    if (i < N) { start = rp[i]; end = rp[i + 1]; }
    int deg = end - start;
    int nEnd = min(n0 + 32, N);
    int s0 = rp[n0];                   // block-uniform
    int e1 = rp[nEnd];

    floatx2 a0 = {0.f, 0.f}, a1 = {0.f, 0.f}, a2 = {0.f, 0.f}, a3 = {0.f, 0.f};
    floatx2 a4 = {0.f, 0.f}, a5 = {0.f, 0.f}, a6 = {0.f, 0.f}, a7 = {0.f, 0.f};
    float dsum = 0.f;

    #define GATH4(ii) (*(const uint4*)(hbase + (((unsigned)(ii) << 7) + c16)))
    #define ACC4(vv) do { \
        a0 += __builtin_amdgcn_cvt_pk_f32_fp8((vv).x, false); \
        a1 += __builtin_amdgcn_cvt_pk_f32_fp8((vv).x, true);  \
        a2 += __builtin_amdgcn_cvt_pk_f32_fp8((vv).y, false); \
        a3 += __builtin_amdgcn_cvt_pk_f32_fp8((vv).y, true);  \
        a4 += __builtin_amdgcn_cvt_pk_f32_fp8((vv).z, false); \
        a5 += __builtin_amdgcn_cvt_pk_f32_fp8((vv).z, true);  \
        a6 += __builtin_amdgcn_cvt_pk_f32_fp8((vv).w, false); \
        a7 += __builtin_amdgcn_cvt_pk_f32_fp8((vv).w, true);  \
    } while (0)

    for (int w0 = s0; w0 < e1; w0 += EW) {
        if (w0 > s0) __syncthreads();   // protect sIdx reuse (uniform cond)
        int wcnt = min(EW, e1 - w0);
        for (int j = t; j < wcnt; j += 256) sIdx[j] = csr[w0 + j];
        __syncthreads();
        int p  = max(start, w0) - w0;
        int pe = min(end, w0 + wcnt) - w0;
        for (; p + 4 <= pe; p += 4) {
            int iA = sIdx[p], iB = sIdx[p + 1], iC = sIdx[p + 2], iD = sIdx[p + 3];
            uint4 vA = GATH4(iA), vB = GATH4(iB), vC = GATH4(iC), vD = GATH4(iD);
            if (col0fix && cc4 == 0)
                dsum += degf[iA] + degf[iB] + degf[iC] + degf[iD];
            ACC4(vA); ACC4(vB); ACC4(vC); ACC4(vD);
        }
        for (; p + 2 <= pe; p += 2) {
            int iA = sIdx[p], iB = sIdx[p + 1];
            uint4 vA = GATH4(iA), vB = GATH4(iB);
            if (col0fix && cc4 == 0) dsum += degf[iA] + degf[iB];
            ACC4(vA); ACC4(vB);
        }
        for (; p < pe; ++p) {
            int iA = sIdx[p];
            uint4 vA = GATH4(iA);
            if (col0fix && cc4 == 0) dsum += degf[iA];
            ACC4(vA);
        }
    }

    if (i < N) {
        float inv;
        if (deg == 0) {                 // keep old h: accumulate own row once
            uint4 v = GATH4(i);
            ACC4(v);
            inv = 1.f;
        } else {
            if (col0fix && cc4 == 0) a0[0] = dsum;   // exact neighbor-deg sum -> logical col 0
            inv = 1.f / (float)deg;
        }
        uint4 r0, r1;
        r0.x = pack_bf2(a0[0] * inv, a0[1] * inv);
        r0.y = pack_bf2(a1[0] * inv, a1[1] * inv);
        r0.z = pack_bf2(a2[0] * inv, a2[1] * inv);
        r0.w = pack_bf2(a3[0] * inv, a3[1] * inv);
        r1.x = pack_bf2(a4[0] * inv, a4[1] * inv);
        r1.y = pack_bf2(a5[0] * inv, a5[1] * inv);
        r1.z = pack_bf2(a6[0] * inv, a6[1] * inv);
        r1.w = pack_bf2(a7[0] * inv, a7[1] * inv);
        int gr0 = 2 * cc4, gr1 = 2 * cc4 + 1;
        *(uint4*)&Al[(g32 * 16 + (gr0 ^ (g32 & 7))) * 4] = r0;
        *(uint4*)&Al[(g32 * 16 + (gr1 ^ (g32 & 7))) * 4] = r1;
    }
    __syncthreads();

    // ---- GEMM phase: wave wv -> rows rh*16..+15, output tiles ot=cq*4..cq*4+3 ----
    {
        int rh = wv & 1, cq = wv >> 1;
        int m = lane & 15, q = lane >> 4;
        int r = rh * 16 + m;           // A row (node) index
        floatx4 acc0 = (floatx4)(0.f), acc1 = (floatx4)(0.f);
        floatx4 acc2 = (floatx4)(0.f), acc3 = (floatx4)(0.f);
        #pragma unroll
        for (int kt = 0; kt < 4; ++kt) {
            short8 af = *(const short8*)&Al[(r * 16 + ((kt * 4 + q) ^ (m & 7))) * 4];
            short8 b0 = *(const short8*)&Wb[((cq * 4 + 0) * 16 + m) * 64 + kt * 16 + q * 4];
            short8 b1 = *(const short8*)&Wb[((cq * 4 + 1) * 16 + m) * 64 + kt * 16 + q * 4];
            short8 b2 = *(const short8*)&Wb[((cq * 4 + 2) * 16 + m) * 64 + kt * 16 + q * 4];
            short8 b3 = *(const short8*)&Wb[((cq * 4 + 3) * 16 + m) * 64 + kt * 16 + q * 4];
            acc0 = __builtin_amdgcn_mfma_f32_16x16x32_bf16(af, b0, acc0, 0, 0, 0);
            acc1 = __builtin_amdgcn_mfma_f32_16x16x32_bf16(af, b1, acc1, 0, 0, 0);
            acc2 = __builtin_amdgcn_mfma_f32_16x16x32_bf16(af, b2, acc2, 0, 0, 0);
            acc3 = __builtin_amdgcn_mfma_f32_16x16x32_bf16(af, b3, acc3, 0, 0, 0);
        }
        float bv0 = bias[(cq * 4 + 0) * 16 + m];
        float bv1 = bias[(cq * 4 + 1) * 16 + m];
        float bv2 = bias[(cq * 4 + 2) * 16 + m];
        float bv3 = bias[(cq * 4 + 3) * 16 + m];
        #pragma unroll
        for (int r4 = 0; r4 < 4; ++r4) {
            int row = rh * 16 + q * 4 + r4;
            float v0 = fmaxf(acc0[r4] + bv0, 0.f);
            float v1 = fmaxf(acc1[r4] + bv1, 0.f);
            float v2 = fmaxf(acc2[r4] + bv2, 0.f);
            float v3 = fmaxf(acc3[r4] + bv3, 0.f);
            if (out8) {
                // phys fp8 bytes m*8 + cq*4 + {0..3} -> one aligned u32
                unsigned pk = __builtin_amdgcn_cvt_pk_fp8_f32(v0, v1, 0, false);
                pk = __builtin_amdgcn_cvt_pk_fp8_f32(v2, v3, pk, true);
                *(unsigned*)((char*)CsS + row * 128 + m * 8 + cq * 4) = pk;
            } else {
                // phys bf16 u32 indices m*4 + cq*2 + {0,1} within row of 64 u32
                CsS[row * 64 + m * 4 + cq * 2 + 0] = pack_bf2(v0, v1);
                CsS[row * 64 + m * 4 + cq * 2 + 1] = pack_bf2(v2, v3);
            }
        }
    }
    __syncthreads();

    // ---- coalesced writeout: 32 rows ----
    {
        int row = t >> 3, gg = t & 7;
        int n = n0 + row;
        if (n < N) {
            if (out8) {
                ((uint4*)out8)[(size_t)n * 8 + gg] =
                    *(const uint4*)((const char*)CsS + row * 128 + gg * 16);
            } else {
                ((uint4*)outb)[(size_t)n * 16 + 2 * gg]     = *(const uint4*)&CsS[row * 64 + 8 * gg];
                ((uint4*)outb)[(size_t)n * 16 + 2 * gg + 1] = *(const uint4*)&CsS[row * 64 + 8 * gg + 4];
            }
        }
    }
    #undef GATH4
    #undef ACC4
}

// ---------------- graph mean-pool + counts: 64-node blocks, 4-way node striping ----------------

__global__ __launch_bounds__(256) void pool_kernel(const unsigned* __restrict__ h,
                                                   const int* __restrict__ gid,
                                                   float* __restrict__ hg,
                                                   float* __restrict__ counts, int N) {
    int c = threadIdx.x & 63;
    int q = threadIdx.x >> 6;
    int n0 = blockIdx.x * 64;
    int nend = min(n0 + 64, N);
    float ax = 0.f, ay = 0.f, cnt = 0.f;
    int cur = -1;
    for (int n = n0 + q; n < nend; n += 4) {
        int g = gid[n];
        if (g != cur) {
            if (cur >= 0) {
                atomicAdd(&hg[cur * HID + 2 * c], ax);
                atomicAdd(&hg[cur * HID + 2 * c + 1], ay);
                if (c == 0) atomicAdd(&counts[cur], cnt);
            }
            ax = ay = cnt = 0.f;
            cur = g;
        }
        unsigned v = h[(size_t)n * 64 + c];
        ax += bf_lo(v); ay += bf_hi(v);
        cnt += 1.f;
    }
    if (cur >= 0) {
        atomicAdd(&hg[cur * HID + 2 * c], ax);
        atomicAdd(&hg[cur * HID + 2 * c + 1], ay);
        if (c == 0) atomicAdd(&counts[cur], cnt);
    }
}

// ---------------- fused classifier head (fp32), one block per graph ----------------

__global__ __launch_bounds__(128) void cls_fused_kernel(const float* __restrict__ hg,
                                                        const float* __restrict__ counts,
                                                        const float* __restrict__ Wc1p,
                                                        const float* __restrict__ Wc1,
                                                        const float* __restrict__ bc1,
                                                        const float* __restrict__ Wc2,
                                                        const float* __restrict__ bc2,
                                                        float* __restrict__ out, int G) {
    __shared__ float x[128];
    __shared__ float y[128];
    __shared__ float red[128];
    int g = blockIdx.x, t = threadIdx.x;
    float inv = 1.f / fmaxf(counts[g], 1.f);
    x[t] = hg[g * HID + t] * inv;
    __syncthreads();
    const float4* wp4 = (const float4*)(Wc1p + t * HID);
    float s = 0.f;
    #pragma unroll
    for (int k4 = 0; k4 < 32; ++k4) {
        float4 w = wp4[k4];
        s += x[k4 * 4] * w.x + x[k4 * 4 + 1] * w.y + x[k4 * 4 + 2] * w.z + x[k4 * 4 + 3] * w.w;
    }
    y[t] = s + bc1[t];
    __syncthreads();
    const float4* w4 = (const float4*)(Wc1 + t * HID);
    float s2 = 0.f;
    #pragma unroll
    for (int k4 = 0; k4 < 32; ++k4) {
        float4 w = w4[k4];
        s2 += y[k4 * 4] * w.x + y[k4 * 4 + 1] * w.y + y[k4 * 4 + 2] * w.z + y[k4 * 4 + 3] * w.w;
    }
    red[t] = (s2 + bc1[t]) * Wc2[t];
    __syncthreads();
    if (t < 64) {
        float r = red[t] + red[t + 64];
        #pragma unroll
        for (int off = 32; off > 0; off >>= 1) r += __shfl_down(r, off);
        if (t == 0) out[g] = r + bc2[0];
    }
}

// ---------------- launch ----------------

extern "C" void kernel_launch(void* const* d_in, const int* in_sizes, int n_in,
                              void* d_out, int out_size, void* d_ws, size_t ws_size,
                              hipStream_t stream) {
    const float* feat = (const float*)d_in[0];
    const int* src    = (const int*)d_in[1];
    const int* dst    = (const int*)d_in[2];
    const int* gid    = (const int*)d_in[3];
    const float* W0  = (const float*)d_in[5];
    const float* b0  = (const float*)d_in[6];
    const float* W1  = (const float*)d_in[7];
    const float* b1  = (const float*)d_in[8];
    const float* W2  = (const float*)d_in[9];
    const float* b2  = (const float*)d_in[10];
    const float* Wc1 = (const float*)d_in[11];
    const float* bc1 = (const float*)d_in[12];
    const float* Wc2 = (const float*)d_in[13];
    const float* bc2 = (const float*)d_in[14];

    const int N = in_sizes[3];
    const int E = in_sizes[1];
    const int G = out_size;

    char* ws = (char*)d_ws;
    size_t off = 0;
    auto alloc = [&](size_t bytes) { void* p = ws + off; off += (bytes + 255) & ~size_t(255); return p; };
    unsigned* h8a    = (unsigned*)alloc((size_t)(N + 1) * 32 * 4);   // fp8 h buffer A (+sentinel row)
    unsigned* h8b    = (unsigned*)alloc((size_t)(N + 1) * 32 * 4);   // fp8 h buffer B (+sentinel row)
    unsigned* hB     = (unsigned*)alloc((size_t)N * 64 * 4);         // bf16 h3 for pool
    float* degf      = (float*)alloc((size_t)(N + 1) * 4);           // exact in-degree (+sentinel 0)
    int* degc        = (int*)alloc((size_t)N * 4);                   // atomic deg counters
    int* cur         = (int*)alloc((size_t)N * 4);                   // forward scatter cursors
    int* csr         = (int*)alloc((size_t)(E + 64) * 4);
    int* rp          = (int*)alloc((size_t)(N + 1) * 4);
    int* bsum        = (int*)alloc(512 * 4);
    unsigned* Wb0    = (unsigned*)alloc(8192 * 4);
    unsigned* Wb1    = (unsigned*)alloc(8192 * 4);
    unsigned* Wb2    = (unsigned*)alloc(8192 * 4);
    float* Wc1p      = (float*)alloc(16384 * 4);
    float* hg        = (float*)alloc((size_t)G * HID * 4);
    float* counts    = (float*)alloc((size_t)G * 4);

    int initg = (N + 255) / 256;
    init_kernel<<<initg, 256, 0, stream>>>(W0, W1, W2, Wc1, Wb0, Wb1, Wb2, Wc1p,
                                           degc, cur, hg, counts, degf, h8a, h8b, G, N);

    int gE = (E + 4095) / 4096;
    int NS = (N + 1 + 1023) / 1024;      // scan blocks (<=128)
    deg_count_kernel<<<gE, 256, 0, stream>>>(dst, degc, E);
    scan1_kernel<<<NS, 1024, 0, stream>>>(degc, rp, degf, bsum, N);
    scan2_kernel<<<1, 128, 0, stream>>>(bsum, NS);
    scan3_kernel<<<NS, 1024, 0, stream>>>(rp, bsum, N);
    scatter_kernel<<<gE, 256, 0, stream>>>(src, dst, cur, rp, csr, E);

    build_h0_kernel<<<(N + 7) / 8, 256, 0, stream>>>(feat, h8a, N);

    int layer_grid = (N + 31) / 32;
    gcn_fused_kernel<<<layer_grid, 256, 0, stream>>>(h8a, h8b, nullptr, Wb0, b0, rp, csr, degf, 1, N);
    gcn_fused_kernel<<<layer_grid, 256, 0, stream>>>(h8b, h8a, nullptr, Wb1, b1, rp, csr, degf, 0, N);
    gcn_fused_kernel<<<layer_grid, 256, 0, stream>>>(h8a, nullptr, hB, Wb2, b2, rp, csr, degf, 0, N);

    pool_kernel<<<(N + 63) / 64, 256, 0, stream>>>(hB, gid, hg, counts, N);

    cls_fused_kernel<<<G, 128, 0, stream>>>(hg, counts, Wc1p, Wc1, bc1, Wc2, bc2,
                                            (float*)d_out, G);
}

// Round 9
// 368.674 us; speedup vs baseline: 1.3063x; 1.2441x over previous
//
#include <hip/hip_runtime.h>
#include <hip/hip_bf16.h>

#define HID 128
#define NRAW 127
#define BSH 8          // 256 nodes per bucket
#define BNODES 256
#define EW 2048        // LDS-staged csr window (edges), fits in Cs union (8 KB)

// Column permutation: all hidden-state tensors (h8a/h8b, hB, hg) store logical
// column l = ot*16+m at physical position p = m*8+ot; inverse invp(p) = (p&7)*16+(p>>3).
// GEMM weights and the first Wc1 application are k-permuted to match.
//
// CSR: bucketed 2-phase counting sort (R5 champion chain). The scan+atomic
// scatter alternative (R8) cost 90us: random 4B csr writes bounce dirty lines
// across the 8 non-coherent XCD L2s (WRITE_SIZE 107MB). Bucketing localizes.
//
// gcn aggregation (R5 champion + block-local degree sort): 8-lane group per
// node, lane owns a 16B uint4 chunk of the node's 128B fp8 row; unroll-4.
// NEW: the block's 32 nodes are rank-sorted by degree in LDS and wave wv takes
// ranks wv*8..wv*8+7 -> its 8 groups have near-equal trip counts, removing the
// ~1.7x within-wave divergence inflation of the latency-bound gather loop.
// A-tile rows keep ORIGINAL local indices -> GEMM/writeout/numerics unchanged.

typedef __attribute__((ext_vector_type(8))) short short8;
typedef __attribute__((ext_vector_type(4))) float floatx4;
typedef __attribute__((ext_vector_type(2))) float floatx2;

__device__ inline unsigned pack_bf2(float x, float y) {
    unsigned bx = __float_as_uint(x);
    unsigned by = __float_as_uint(y);
    bx += 0x7fffu + ((bx >> 16) & 1u);   // RNE
    by += 0x7fffu + ((by >> 16) & 1u);
    return (bx >> 16) | (by & 0xffff0000u);
}
__device__ inline float bf_lo(unsigned u) { return __uint_as_float(u << 16); }
__device__ inline float bf_hi(unsigned u) { return __uint_as_float(u & 0xffff0000u); }

// ---------------- init: zeros + permuted weight packs + sentinel rows ----------------

__global__ void init_kernel(const float* __restrict__ W0, const float* __restrict__ W1,
                            const float* __restrict__ W2, const float* __restrict__ Wc1,
                            unsigned* __restrict__ O0, unsigned* __restrict__ O1,
                            unsigned* __restrict__ O2, float* __restrict__ Wc1p,
                            int* __restrict__ gbucket, float* __restrict__ hg,
                            float* __restrict__ counts,
                            unsigned* __restrict__ h8a, unsigned* __restrict__ h8b,
                            int G, int N) {
    int id = blockIdx.x * blockDim.x + threadIdx.x;
    if (id < 512) gbucket[id] = 0;
    if (id < G * HID) hg[id] = 0.f;
    if (id < G) counts[id] = 0.f;
    if (id < 32) {                       // sentinel zero rows (safety)
        h8a[(size_t)N * 32 + id] = 0u;
        h8b[(size_t)N * 32 + id] = 0u;
    }
    if (id < 16384) {   // Wc1 with permuted k for the first head matmul
        int t = id >> 7, p = id & 127;
        Wc1p[id] = Wc1[t * 128 + ((p & 7) * 16 + (p >> 3))];
    }
    if (id < 3 * 8192) {   // GCN weights, bf16, k-permuted
        int sel = id >> 13, l = id & 8191;
        const float* W = sel == 0 ? W0 : (sel == 1 ? W1 : W2);
        unsigned* O = sel == 0 ? O0 : (sel == 1 ? O1 : O2);
        int o = l >> 6, pp = (l & 63) * 2;
        int k0 = (pp & 7) * 16 + (pp >> 3);
        int k1 = ((pp + 1) & 7) * 16 + ((pp + 1) >> 3);
        O[l] = pack_bf2(W[o * 128 + k0], W[o * 128 + k1]);
    }
}

// ---------------- CSR build: bucketed 2-phase counting sort ----------------

__global__ __launch_bounds__(256) void bucket_count_kernel(const int* __restrict__ dst,
                                                           int* __restrict__ gbucket,
                                                           int E, int NB) {
    __shared__ int hist[512];
    int t = threadIdx.x;
    for (int b = t; b < NB; b += 256) hist[b] = 0;
    __syncthreads();
    int base = blockIdx.x * 4096;
    #pragma unroll
    for (int j = 0; j < 16; ++j) {
        int e = base + j * 256 + t;
        if (e < E) atomicAdd(&hist[dst[e] >> BSH], 1);
    }
    __syncthreads();
    for (int b = t; b < NB; b += 256) {
        int v = hist[b];
        if (v) atomicAdd(&gbucket[b], v);
    }
}

__global__ void bucket_scan_kernel(const int* __restrict__ gbucket, int* __restrict__ bstart,
                                   int* __restrict__ gcur, int NB, int E) {
    __shared__ int sm[512];
    int t = threadIdx.x;
    int v = (t < NB) ? gbucket[t] : 0;
    sm[t] = v;
    __syncthreads();
    for (int off = 1; off < 512; off <<= 1) {
        int add = (t >= off) ? sm[t - off] : 0;
        __syncthreads();
        sm[t] += add;
        __syncthreads();
    }
    if (t < NB) {
        int ex = sm[t] - v;
        bstart[t] = ex;
        gcur[t] = ex;
    }
    if (t == 0) bstart[NB] = E;
}

// staging entry: (src << 8) | (dst & 255)  -- 4 B/edge (src < 2^24, local dst 8 bits)
__global__ __launch_bounds__(256) void bucket_scatter_kernel(const int* __restrict__ src,
                                                             const int* __restrict__ dst,
                                                             int* __restrict__ gcur,
                                                             unsigned* __restrict__ staging,
                                                             int E, int NB) {
    __shared__ int hist[512];
    __shared__ int base[512];
    int t = threadIdx.x;
    for (int b = t; b < NB; b += 256) hist[b] = 0;
    __syncthreads();
    int s[16], d[16], r[16];
    int e0 = blockIdx.x * 4096;
    #pragma unroll
    for (int j = 0; j < 16; ++j) {
        int e = e0 + j * 256 + t;
        if (e < E) {
            s[j] = src[e];
            d[j] = dst[e];
            r[j] = atomicAdd(&hist[d[j] >> BSH], 1);
        } else d[j] = -1;
    }
    __syncthreads();
    for (int b = t; b < NB; b += 256) {
        int v = hist[b];
        base[b] = v ? atomicAdd(&gcur[b], v) : 0;
    }
    __syncthreads();
    #pragma unroll
    for (int j = 0; j < 16; ++j) {
        if (d[j] >= 0) {
            int b = d[j] >> BSH;
            staging[base[b] + r[j]] = ((unsigned)s[j] << 8) | ((unsigned)d[j] & 255u);
        }
    }
}

__global__ __launch_bounds__(256) void csr_build_kernel(const unsigned* __restrict__ staging,
                                                        const int* __restrict__ bstart,
                                                        int* __restrict__ rp, int* __restrict__ csr,
                                                        float* __restrict__ degf,
                                                        int N, int E, int NB) {
    __shared__ int hist[256];
    __shared__ int sm[256];
    __shared__ int excl[256];
    __shared__ int cnt[256];
    int t = threadIdx.x;
    int b = blockIdx.x;
    int nbase = b << BSH;
    int s0 = bstart[b], e1 = bstart[b + 1];
    hist[t] = 0;
    __syncthreads();
    for (int i = s0 + t; i < e1; i += 256) {
        unsigned p = staging[i];
        atomicAdd(&hist[p & (BNODES - 1)], 1);
    }
    __syncthreads();
    int h = hist[t];
    sm[t] = h;
    __syncthreads();
    for (int off = 1; off < 256; off <<= 1) {
        int add = (t >= off) ? sm[t - off] : 0;
        __syncthreads();
        sm[t] += add;
        __syncthreads();
    }
    excl[t] = sm[t] - h;
    cnt[t] = 0;
    int n = nbase + t;
    if (n < N) {
        rp[n] = s0 + (sm[t] - h);
        degf[n] = (float)h;
    }
    if (b == NB - 1 && t == 0) {
        rp[N] = E;
        degf[N] = 0.f;                     // sentinel degree
    }
    __syncthreads();
    for (int i = s0 + t; i < e1; i += 256) {
        unsigned p = staging[i];
        int dl = p & (BNODES - 1);
        int pos = s0 + excl[dl] + atomicAdd(&cnt[dl], 1);
        csr[pos] = (int)(p >> 8);
    }
}

// ---------------- h0 in fp8, permuted layout, coalesced via LDS row staging ----------------

__global__ __launch_bounds__(256) void build_h0_kernel(const float* __restrict__ feat,
                                                       unsigned* __restrict__ h8, int N) {
    __shared__ float lf[8 * NRAW];
    int t = threadIdx.x;
    int n0 = blockIdx.x * 8;
    int nrows = min(8, N - n0);
    int total = nrows * NRAW;
    for (int j = t; j < total; j += 256) lf[j] = feat[(size_t)n0 * NRAW + j];
    __syncthreads();
    int n = t >> 5, c = t & 31;
    if (n < nrows) {
        const float* fr = lf + n * NRAW;
        int base = c >> 1, hb = (c & 1) * 4;
        float f[4];
        #pragma unroll
        for (int j = 0; j < 4; ++j) {
            int l = (hb + j) * 16 + base;   // logical col at physical byte 4c+j
            f[j] = (l == 0) ? 0.f : fr[l - 1];
        }
        unsigned w = __builtin_amdgcn_cvt_pk_fp8_f32(f[0], f[1], 0, false);
        w = __builtin_amdgcn_cvt_pk_fp8_f32(f[2], f[3], w, true);
        h8[(size_t)(n0 + n) * 32 + c] = w;
    }
}

// ---------------- fused GCN layer: degree-sorted 8-lane-group agg -> LDS A-tile -> MFMA ----------------
// 32 nodes per 256-thread block. Lane = (group grp = lane>>3, chunk cc4 = lane&7).
// Setup ranks the block's 32 nodes by degree (32-thread counting rank); wave wv's
// 8 groups take sorted ranks wv*8..wv*8+7 (similar degrees -> minimal masked
// iterations). lr = original local index keeps A-tile/GEMM/writeout unchanged.
// Inner gather loop is textually identical to the 356us champion.

__global__ __launch_bounds__(256, 4) void gcn_fused_kernel(const unsigned* __restrict__ h8,
                                                           unsigned* __restrict__ out8,
                                                           unsigned* __restrict__ outb,
                                                           const unsigned* __restrict__ Wb,
                                                           const float* __restrict__ bias,
                                                           const int* __restrict__ rp,
                                                           const int* __restrict__ csr,
                                                           const float* __restrict__ degf,
                                                           int col0fix, int N) {
    __shared__ unsigned Al[32 * 64];     // A tile, swizzled: row r granule gr at Al[(r*16 + (gr^(r&7)))*4]
    __shared__ unsigned CsS[32 * 64];    // C staging; first EW*4 bytes double as sIdx during agg
    __shared__ int rpsS[33];
    __shared__ int degS[32];
    __shared__ int ordS[32];
    int* sIdx = (int*)CsS;
    int t = threadIdx.x;
    int wv = t >> 6, lane = t & 63;
    int grp = lane >> 3;               // node group 0..7 within wave
    int cc4 = lane & 7;                // 16B chunk 0..7
    int n0 = blockIdx.x * 32;
    int g32 = wv * 8 + grp;            // sorted rank this group handles
    const char* hbase = (const char*)h8;
    unsigned c16 = (unsigned)cc4 * 16u;

    if (t < 33) rpsS[t] = rp[min(n0 + t, N)];
    __syncthreads();
    if (t < 32) degS[t] = rpsS[t + 1] - rpsS[t];
    __syncthreads();
    if (t < 32) {
        int d = degS[t], rank = 0;
        #pragma unroll 8
        for (int j = 0; j < 32; ++j) {
            int dj = degS[j];
            rank += (dj < d) || (dj == d && j < t);
        }
        ordS[rank] = t;
    }
    __syncthreads();
    int lr = ordS[g32];                // original block-local node index
    int i = n0 + lr;
    int start = rpsS[lr], end = rpsS[lr + 1];
    int deg = end - start;
    int s0 = rpsS[0];                  // block-uniform
    int e1 = rpsS[32];

    floatx2 a0 = {0.f, 0.f}, a1 = {0.f, 0.f}, a2 = {0.f, 0.f}, a3 = {0.f, 0.f};
    floatx2 a4 = {0.f, 0.f}, a5 = {0.f, 0.f}, a6 = {0.f, 0.f}, a7 = {0.f, 0.f};
    float dsum = 0.f;

    #define GATH4(ii) (*(const uint4*)(hbase + (((unsigned)(ii) << 7) + c16)))
    #define ACC4(vv) do { \
        a0 += __builtin_amdgcn_cvt_pk_f32_fp8((vv).x, false); \
        a1 += __builtin_amdgcn_cvt_pk_f32_fp8((vv).x, true);  \
        a2 += __builtin_amdgcn_cvt_pk_f32_fp8((vv).y, false); \
        a3 += __builtin_amdgcn_cvt_pk_f32_fp8((vv).y, true);  \
        a4 += __builtin_amdgcn_cvt_pk_f32_fp8((vv).z, false); \
        a5 += __builtin_amdgcn_cvt_pk_f32_fp8((vv).z, true);  \
        a6 += __builtin_amdgcn_cvt_pk_f32_fp8((vv).w, false); \
        a7 += __builtin_amdgcn_cvt_pk_f32_fp8((vv).w, true);  \
    } while (0)

    for (int w0 = s0; w0 < e1; w0 += EW) {
        if (w0 > s0) __syncthreads();   // protect sIdx reuse (uniform cond)
        int wcnt = min(EW, e1 - w0);
        for (int j = t; j < wcnt; j += 256) sIdx[j] = csr[w0 + j];
        __syncthreads();
        int p  = max(start, w0) - w0;
        int pe = min(end, w0 + wcnt) - w0;
        for (; p + 4 <= pe; p += 4) {
            int iA = sIdx[p], iB = sIdx[p + 1], iC = sIdx[p + 2], iD = sIdx[p + 3];
            uint4 vA = GATH4(iA), vB = GATH4(iB), vC = GATH4(iC), vD = GATH4(iD);
            if (col0fix && cc4 == 0)
                dsum += degf[iA] + degf[iB] + degf[iC] + degf[iD];
            ACC4(vA); ACC4(vB); ACC4(vC); ACC4(vD);
        }
        for (; p + 2 <= pe; p += 2) {
            int iA = sIdx[p], iB = sIdx[p + 1];
            uint4 vA = GATH4(iA), vB = GATH4(iB);
            if (col0fix && cc4 == 0) dsum += degf[iA] + degf[iB];
            ACC4(vA); ACC4(vB);
        }
        for (; p < pe; ++p) {
            int iA = sIdx[p];
            uint4 vA = GATH4(iA);
            if (col0fix && cc4 == 0) dsum += degf[iA];
            ACC4(vA);
        }
    }

    if (i < N) {
        float inv;
        if (deg == 0) {                 // keep old h: accumulate own row once
            uint4 v = GATH4(i);
            ACC4(v);
            inv = 1.f;
        } else {
            if (col0fix && cc4 == 0) a0[0] = dsum;   // exact neighbor-deg sum -> logical col 0
            inv = 1.f / (float)deg;
        }
        uint4 r0, r1;
        r0.x = pack_bf2(a0[0] * inv, a0[1] * inv);
        r0.y = pack_bf2(a1[0] * inv, a1[1] * inv);
        r0.z = pack_bf2(a2[0] * inv, a2[1] * inv);
        r0.w = pack_bf2(a3[0] * inv, a3[1] * inv);
        r1.x = pack_bf2(a4[0] * inv, a4[1] * inv);
        r1.y = pack_bf2(a5[0] * inv, a5[1] * inv);
        r1.z = pack_bf2(a6[0] * inv, a6[1] * inv);
        r1.w = pack_bf2(a7[0] * inv, a7[1] * inv);
        int gr0 = 2 * cc4, gr1 = 2 * cc4 + 1;
        *(uint4*)&Al[(lr * 16 + (gr0 ^ (lr & 7))) * 4] = r0;
        *(uint4*)&Al[(lr * 16 + (gr1 ^ (lr & 7))) * 4] = r1;
    }
    __syncthreads();

    // ---- GEMM phase: wave wv -> rows rh*16..+15, output tiles ot=cq*4..cq*4+3 ----
    {
        int rh = wv & 1, cq = wv >> 1;
        int m = lane & 15, q = lane >> 4;
        int r = rh * 16 + m;           // A row (node) index
        floatx4 acc0 = (floatx4)(0.f), acc1 = (floatx4)(0.f);
        floatx4 acc2 = (floatx4)(0.f), acc3 = (floatx4)(0.f);
        #pragma unroll
        for (int kt = 0; kt < 4; ++kt) {
            short8 af = *(const short8*)&Al[(r * 16 + ((kt * 4 + q) ^ (m & 7))) * 4];
            short8 b0 = *(const short8*)&Wb[((cq * 4 + 0) * 16 + m) * 64 + kt * 16 + q * 4];
            short8 b1 = *(const short8*)&Wb[((cq * 4 + 1) * 16 + m) * 64 + kt * 16 + q * 4];
            short8 b2 = *(const short8*)&Wb[((cq * 4 + 2) * 16 + m) * 64 + kt * 16 + q * 4];
            short8 b3 = *(const short8*)&Wb[((cq * 4 + 3) * 16 + m) * 64 + kt * 16 + q * 4];
            acc0 = __builtin_amdgcn_mfma_f32_16x16x32_bf16(af, b0, acc0, 0, 0, 0);
            acc1 = __builtin_amdgcn_mfma_f32_16x16x32_bf16(af, b1, acc1, 0, 0, 0);
            acc2 = __builtin_amdgcn_mfma_f32_16x16x32_bf16(af, b2, acc2, 0, 0, 0);
            acc3 = __builtin_amdgcn_mfma_f32_16x16x32_bf16(af, b3, acc3, 0, 0, 0);
        }
        float bv0 = bias[(cq * 4 + 0) * 16 + m];
        float bv1 = bias[(cq * 4 + 1) * 16 + m];
        float bv2 = bias[(cq * 4 + 2) * 16 + m];
        float bv3 = bias[(cq * 4 + 3) * 16 + m];
        #pragma unroll
        for (int r4 = 0; r4 < 4; ++r4) {
            int row = rh * 16 + q * 4 + r4;
            float v0 = fmaxf(acc0[r4] + bv0, 0.f);
            float v1 = fmaxf(acc1[r4] + bv1, 0.f);
            float v2 = fmaxf(acc2[r4] + bv2, 0.f);
            float v3 = fmaxf(acc3[r4] + bv3, 0.f);
            if (out8) {
                // phys fp8 bytes m*8 + cq*4 + {0..3} -> one aligned u32
                unsigned pk = __builtin_amdgcn_cvt_pk_fp8_f32(v0, v1, 0, false);
                pk = __builtin_amdgcn_cvt_pk_fp8_f32(v2, v3, pk, true);
                *(unsigned*)((char*)CsS + row * 128 + m * 8 + cq * 4) = pk;
            } else {
                // phys bf16 u32 indices m*4 + cq*2 + {0,1} within row of 64 u32
                CsS[row * 64 + m * 4 + cq * 2 + 0] = pack_bf2(v0, v1);
                CsS[row * 64 + m * 4 + cq * 2 + 1] = pack_bf2(v2, v3);
            }
        }
    }
    __syncthreads();

    // ---- coalesced writeout: 32 rows ----
    {
        int row = t >> 3, gg = t & 7;
        int n = n0 + row;
        if (n < N) {
            if (out8) {
                ((uint4*)out8)[(size_t)n * 8 + gg] =
                    *(const uint4*)((const char*)CsS + row * 128 + gg * 16);
            } else {
                ((uint4*)outb)[(size_t)n * 16 + 2 * gg]     = *(const uint4*)&CsS[row * 64 + 8 * gg];
                ((uint4*)outb)[(size_t)n * 16 + 2 * gg + 1] = *(const uint4*)&CsS[row * 64 + 8 * gg + 4];
            }
        }
    }
    #undef GATH4
    #undef ACC4
}

// ---------------- graph mean-pool + counts: 64-node blocks, 4-way node striping ----------------

__global__ __launch_bounds__(256) void pool_kernel(const unsigned* __restrict__ h,
                                                   const int* __restrict__ gid,
                                                   float* __restrict__ hg,
                                                   float* __restrict__ counts, int N) {
    int c = threadIdx.x & 63;
    int q = threadIdx.x >> 6;
    int n0 = blockIdx.x * 64;
    int nend = min(n0 + 64, N);
    float ax = 0.f, ay = 0.f, cnt = 0.f;
    int cur = -1;
    for (int n = n0 + q; n < nend; n += 4) {
        int g = gid[n];
        if (g != cur) {
            if (cur >= 0) {
                atomicAdd(&hg[cur * HID + 2 * c], ax);
                atomicAdd(&hg[cur * HID + 2 * c + 1], ay);
                if (c == 0) atomicAdd(&counts[cur], cnt);
            }
            ax = ay = cnt = 0.f;
            cur = g;
        }
        unsigned v = h[(size_t)n * 64 + c];
        ax += bf_lo(v); ay += bf_hi(v);
        cnt += 1.f;
    }
    if (cur >= 0) {
        atomicAdd(&hg[cur * HID + 2 * c], ax);
        atomicAdd(&hg[cur * HID + 2 * c + 1], ay);
        if (c == 0) atomicAdd(&counts[cur], cnt);
    }
}

// ---------------- fused classifier head (fp32), one block per graph ----------------

__global__ __launch_bounds__(128) void cls_fused_kernel(const float* __restrict__ hg,
                                                        const float* __restrict__ counts,
                                                        const float* __restrict__ Wc1p,
                                                        const float* __restrict__ Wc1,
                                                        const float* __restrict__ bc1,
                                                        const float* __restrict__ Wc2,
                                                        const float* __restrict__ bc2,
                                                        float* __restrict__ out, int G) {
    __shared__ float x[128];
    __shared__ float y[128];
    __shared__ float red[128];
    int g = blockIdx.x, t = threadIdx.x;
    float inv = 1.f / fmaxf(counts[g], 1.f);
    x[t] = hg[g * HID + t] * inv;
    __syncthreads();
    const float4* wp4 = (const float4*)(Wc1p + t * HID);
    float s = 0.f;
    #pragma unroll
    for (int k4 = 0; k4 < 32; ++k4) {
        float4 w = wp4[k4];
        s += x[k4 * 4] * w.x + x[k4 * 4 + 1] * w.y + x[k4 * 4 + 2] * w.z + x[k4 * 4 + 3] * w.w;
    }
    y[t] = s + bc1[t];
    __syncthreads();
    const float4* w4 = (const float4*)(Wc1 + t * HID);
    float s2 = 0.f;
    #pragma unroll
    for (int k4 = 0; k4 < 32; ++k4) {
        float4 w = w4[k4];
        s2 += y[k4 * 4] * w.x + y[k4 * 4 + 1] * w.y + y[k4 * 4 + 2] * w.z + y[k4 * 4 + 3] * w.w;
    }
    red[t] = (s2 + bc1[t]) * Wc2[t];
    __syncthreads();
    if (t < 64) {
        float r = red[t] + red[t + 64];
        #pragma unroll
        for (int off = 32; off > 0; off >>= 1) r += __shfl_down(r, off);
        if (t == 0) out[g] = r + bc2[0];
    }
}

// ---------------- launch ----------------

extern "C" void kernel_launch(void* const* d_in, const int* in_sizes, int n_in,
                              void* d_out, int out_size, void* d_ws, size_t ws_size,
                              hipStream_t stream) {
    const float* feat = (const float*)d_in[0];
    const int* src    = (const int*)d_in[1];
    const int* dst    = (const int*)d_in[2];
    const int* gid    = (const int*)d_in[3];
    const float* W0  = (const float*)d_in[5];
    const float* b0  = (const float*)d_in[6];
    const float* W1  = (const float*)d_in[7];
    const float* b1  = (const float*)d_in[8];
    const float* W2  = (const float*)d_in[9];
    const float* b2  = (const float*)d_in[10];
    const float* Wc1 = (const float*)d_in[11];
    const float* bc1 = (const float*)d_in[12];
    const float* Wc2 = (const float*)d_in[13];
    const float* bc2 = (const float*)d_in[14];

    const int N = in_sizes[3];
    const int E = in_sizes[1];
    const int G = out_size;
    const int NB = (N + BNODES - 1) >> BSH;

    char* ws = (char*)d_ws;
    size_t off = 0;
    auto alloc = [&](size_t bytes) { void* p = ws + off; off += (bytes + 255) & ~size_t(255); return p; };
    unsigned* h8a    = (unsigned*)alloc((size_t)(N + 1) * 32 * 4);   // fp8 h buffer A (+sentinel row)
    unsigned* h8b    = (unsigned*)alloc((size_t)(N + 1) * 32 * 4);   // fp8 h buffer B (+sentinel row)
    unsigned* hB     = (unsigned*)alloc((size_t)N * 64 * 4);         // bf16 h3 for pool
    float* degf      = (float*)alloc((size_t)(N + 1) * 4);           // exact in-degree (+sentinel 0)
    unsigned* staging = (unsigned*)alloc((size_t)E * 4);             // packed (src<<8)|dst_local
    int* csr         = (int*)alloc((size_t)(E + 64) * 4);
    int* rp          = (int*)alloc((size_t)(N + 1) * 4);
    int* gbucket     = (int*)alloc(512 * 4);
    int* bstart      = (int*)alloc(513 * 4);
    int* gcur        = (int*)alloc(512 * 4);
    unsigned* Wb0    = (unsigned*)alloc(8192 * 4);
    unsigned* Wb1    = (unsigned*)alloc(8192 * 4);
    unsigned* Wb2    = (unsigned*)alloc(8192 * 4);
    float* Wc1p      = (float*)alloc(16384 * 4);
    float* hg        = (float*)alloc((size_t)G * HID * 4);
    float* counts    = (float*)alloc((size_t)G * 4);

    init_kernel<<<96, 256, 0, stream>>>(W0, W1, W2, Wc1, Wb0, Wb1, Wb2, Wc1p,
                                        gbucket, hg, counts, h8a, h8b, G, N);

    int gE = (E + 4095) / 4096;
    bucket_count_kernel<<<gE, 256, 0, stream>>>(dst, gbucket, E, NB);
    bucket_scan_kernel<<<1, 512, 0, stream>>>(gbucket, bstart, gcur, NB, E);
    bucket_scatter_kernel<<<gE, 256, 0, stream>>>(src, dst, gcur, staging, E, NB);
    csr_build_kernel<<<NB, 256, 0, stream>>>(staging, bstart, rp, csr, degf, N, E, NB);

    build_h0_kernel<<<(N + 7) / 8, 256, 0, stream>>>(feat, h8a, N);

    int layer_grid = (N + 31) / 32;
    gcn_fused_kernel<<<layer_grid, 256, 0, stream>>>(h8a, h8b, nullptr, Wb0, b0, rp, csr, degf, 1, N);
    gcn_fused_kernel<<<layer_grid, 256, 0, stream>>>(h8b, h8a, nullptr, Wb1, b1, rp, csr, degf, 0, N);
    gcn_fused_kernel<<<layer_grid, 256, 0, stream>>>(h8a, nullptr, hB, Wb2, b2, rp, csr, degf, 0, N);

    pool_kernel<<<(N + 63) / 64, 256, 0, stream>>>(hB, gid, hg, counts, N);

    cls_fused_kernel<<<G, 128, 0, stream>>>(hg, counts, Wc1p, Wc1, bc1, Wc2, bc2,
                                            (float*)d_out, G);
}

// Round 10
// 356.312 us; speedup vs baseline: 1.3517x; 1.0347x over previous
//
#include <hip/hip_runtime.h>
#include <hip/hip_bf16.h>

#define HID 128
#define NRAW 127
#define BSH 8          // 256 nodes per bucket
#define BNODES 256
#define EW 2048        // LDS-staged csr window (edges), fits in Cs union (8 KB)
#define BCAP 5120      // csr_build LDS edge stage (20 KB); avg 4096/bucket, +16 sigma

// Column permutation: all hidden-state tensors (h8a/h8b, hB, hg) store logical
// column l = ot*16+m at physical position p = m*8+ot; inverse invp(p) = (p&7)*16+(p>>3).
// GEMM weights and the first Wc1 application are k-permuted to match.
//
// CSR: bucketed 2-phase counting sort. csr_build stages the bucket's edges in
// LDS (single global pass; block-uniform fallback to the 2-pass path if a
// bucket exceeds BCAP). R8 showed non-bucketed scatter costs 90us (cross-XCD
// dirty-line bouncing, WRITE_SIZE 107MB) -- bucketing localizes writes.
//
// gcn_fused_kernel is byte-exact the 356us champion (R5): uint4 8-lane groups,
// unroll-4, LDS sIdx window unioned with Cs, XOR-swizzled A-tile. R9's degree
// sort regressed (~+4.5us/layer setup+codegen cost) and confirmed the gather
// phase is at a memory-parallelism ceiling -- do not perturb this kernel.

typedef __attribute__((ext_vector_type(8))) short short8;
typedef __attribute__((ext_vector_type(4))) float floatx4;
typedef __attribute__((ext_vector_type(2))) float floatx2;

__device__ inline unsigned pack_bf2(float x, float y) {
    unsigned bx = __float_as_uint(x);
    unsigned by = __float_as_uint(y);
    bx += 0x7fffu + ((bx >> 16) & 1u);   // RNE
    by += 0x7fffu + ((by >> 16) & 1u);
    return (bx >> 16) | (by & 0xffff0000u);
}
__device__ inline float bf_lo(unsigned u) { return __uint_as_float(u << 16); }
__device__ inline float bf_hi(unsigned u) { return __uint_as_float(u & 0xffff0000u); }

// ---------------- init: zeros + permuted weight packs + sentinel rows ----------------

__global__ void init_kernel(const float* __restrict__ W0, const float* __restrict__ W1,
                            const float* __restrict__ W2, const float* __restrict__ Wc1,
                            unsigned* __restrict__ O0, unsigned* __restrict__ O1,
                            unsigned* __restrict__ O2, float* __restrict__ Wc1p,
                            int* __restrict__ gbucket, float* __restrict__ hg,
                            float* __restrict__ counts,
                            unsigned* __restrict__ h8a, unsigned* __restrict__ h8b,
                            int G, int N) {
    int id = blockIdx.x * blockDim.x + threadIdx.x;
    if (id < 512) gbucket[id] = 0;
    if (id < G * HID) hg[id] = 0.f;
    if (id < G) counts[id] = 0.f;
    if (id < 32) {                       // sentinel zero rows (safety)
        h8a[(size_t)N * 32 + id] = 0u;
        h8b[(size_t)N * 32 + id] = 0u;
    }
    if (id < 16384) {   // Wc1 with permuted k for the first head matmul
        int t = id >> 7, p = id & 127;
        Wc1p[id] = Wc1[t * 128 + ((p & 7) * 16 + (p >> 3))];
    }
    if (id < 3 * 8192) {   // GCN weights, bf16, k-permuted
        int sel = id >> 13, l = id & 8191;
        const float* W = sel == 0 ? W0 : (sel == 1 ? W1 : W2);
        unsigned* O = sel == 0 ? O0 : (sel == 1 ? O1 : O2);
        int o = l >> 6, pp = (l & 63) * 2;
        int k0 = (pp & 7) * 16 + (pp >> 3);
        int k1 = ((pp + 1) & 7) * 16 + ((pp + 1) >> 3);
        O[l] = pack_bf2(W[o * 128 + k0], W[o * 128 + k1]);
    }
}

// ---------------- CSR build: bucketed 2-phase counting sort ----------------

__global__ __launch_bounds__(256) void bucket_count_kernel(const int* __restrict__ dst,
                                                           int* __restrict__ gbucket,
                                                           int E, int NB) {
    __shared__ int hist[512];
    int t = threadIdx.x;
    for (int b = t; b < NB; b += 256) hist[b] = 0;
    __syncthreads();
    int base = blockIdx.x * 4096;
    #pragma unroll
    for (int j = 0; j < 16; ++j) {
        int e = base + j * 256 + t;
        if (e < E) atomicAdd(&hist[dst[e] >> BSH], 1);
    }
    __syncthreads();
    for (int b = t; b < NB; b += 256) {
        int v = hist[b];
        if (v) atomicAdd(&gbucket[b], v);
    }
}

__global__ void bucket_scan_kernel(const int* __restrict__ gbucket, int* __restrict__ bstart,
                                   int* __restrict__ gcur, int NB, int E) {
    __shared__ int sm[512];
    int t = threadIdx.x;
    int v = (t < NB) ? gbucket[t] : 0;
    sm[t] = v;
    __syncthreads();
    for (int off = 1; off < 512; off <<= 1) {
        int add = (t >= off) ? sm[t - off] : 0;
        __syncthreads();
        sm[t] += add;
        __syncthreads();
    }
    if (t < NB) {
        int ex = sm[t] - v;
        bstart[t] = ex;
        gcur[t] = ex;
    }
    if (t == 0) bstart[NB] = E;
}

// staging entry: (src << 8) | (dst & 255)  -- 4 B/edge (src < 2^24, local dst 8 bits)
__global__ __launch_bounds__(256) void bucket_scatter_kernel(const int* __restrict__ src,
                                                             const int* __restrict__ dst,
                                                             int* __restrict__ gcur,
                                                             unsigned* __restrict__ staging,
                                                             int E, int NB) {
    __shared__ int hist[512];
    __shared__ int base[512];
    int t = threadIdx.x;
    for (int b = t; b < NB; b += 256) hist[b] = 0;
    __syncthreads();
    int s[16], d[16], r[16];
    int e0 = blockIdx.x * 4096;
    #pragma unroll
    for (int j = 0; j < 16; ++j) {
        int e = e0 + j * 256 + t;
        if (e < E) {
            s[j] = src[e];
            d[j] = dst[e];
            r[j] = atomicAdd(&hist[d[j] >> BSH], 1);
        } else d[j] = -1;
    }
    __syncthreads();
    for (int b = t; b < NB; b += 256) {
        int v = hist[b];
        base[b] = v ? atomicAdd(&gcur[b], v) : 0;
    }
    __syncthreads();
    #pragma unroll
    for (int j = 0; j < 16; ++j) {
        if (d[j] >= 0) {
            int b = d[j] >> BSH;
            staging[base[b] + r[j]] = ((unsigned)s[j] << 8) | ((unsigned)d[j] & 255u);
        }
    }
}

// Single-pass: stage this bucket's edges into LDS (se), histogram + scan +
// place entirely from LDS. Block-uniform fallback to the global 2-pass path
// if the bucket exceeds BCAP (never for Poisson(4096) buckets; safety only).
__global__ __launch_bounds__(256) void csr_build_kernel(const unsigned* __restrict__ staging,
                                                        const int* __restrict__ bstart,
                                                        int* __restrict__ rp, int* __restrict__ csr,
                                                        float* __restrict__ degf,
                                                        int N, int E, int NB) {
    __shared__ int hist[256];
    __shared__ int sm[256];
    __shared__ int excl[256];
    __shared__ int cnt[256];
    __shared__ unsigned se[BCAP];
    int t = threadIdx.x;
    int b = blockIdx.x;
    int nbase = b << BSH;
    int s0 = bstart[b], e1 = bstart[b + 1];
    int cntE = e1 - s0;                // block-uniform
    bool lds = (cntE <= BCAP);
    hist[t] = 0;
    __syncthreads();
    if (lds) {
        for (int i = t; i < cntE; i += 256) {
            unsigned p = staging[s0 + i];
            se[i] = p;
            atomicAdd(&hist[p & (BNODES - 1)], 1);
        }
    } else {
        for (int i = s0 + t; i < e1; i += 256) {
            unsigned p = staging[i];
            atomicAdd(&hist[p & (BNODES - 1)], 1);
        }
    }
    __syncthreads();
    int h = hist[t];
    sm[t] = h;
    __syncthreads();
    for (int off = 1; off < 256; off <<= 1) {
        int add = (t >= off) ? sm[t - off] : 0;
        __syncthreads();
        sm[t] += add;
        __syncthreads();
    }
    excl[t] = sm[t] - h;
    cnt[t] = 0;
    int n = nbase + t;
    if (n < N) {
        rp[n] = s0 + (sm[t] - h);
        degf[n] = (float)h;
    }
    if (b == NB - 1 && t == 0) {
        rp[N] = E;
        degf[N] = 0.f;                     // sentinel degree
    }
    __syncthreads();
    if (lds) {
        for (int i = t; i < cntE; i += 256) {
            unsigned p = se[i];
            int dl = p & (BNODES - 1);
            int pos = s0 + excl[dl] + atomicAdd(&cnt[dl], 1);
            csr[pos] = (int)(p >> 8);
        }
    } else {
        for (int i = s0 + t; i < e1; i += 256) {
            unsigned p = staging[i];
            int dl = p & (BNODES - 1);
            int pos = s0 + excl[dl] + atomicAdd(&cnt[dl], 1);
            csr[pos] = (int)(p >> 8);
        }
    }
}

// ---------------- h0 in fp8, permuted layout, coalesced via LDS row staging ----------------

__global__ __launch_bounds__(256) void build_h0_kernel(const float* __restrict__ feat,
                                                       unsigned* __restrict__ h8, int N) {
    __shared__ float lf[8 * NRAW];
    int t = threadIdx.x;
    int n0 = blockIdx.x * 8;
    int nrows = min(8, N - n0);
    int total = nrows * NRAW;
    for (int j = t; j < total; j += 256) lf[j] = feat[(size_t)n0 * NRAW + j];
    __syncthreads();
    int n = t >> 5, c = t & 31;
    if (n < nrows) {
        const float* fr = lf + n * NRAW;
        int base = c >> 1, hb = (c & 1) * 4;
        float f[4];
        #pragma unroll
        for (int j = 0; j < 4; ++j) {
            int l = (hb + j) * 16 + base;   // logical col at physical byte 4c+j
            f[j] = (l == 0) ? 0.f : fr[l - 1];
        }
        unsigned w = __builtin_amdgcn_cvt_pk_fp8_f32(f[0], f[1], 0, false);
        w = __builtin_amdgcn_cvt_pk_fp8_f32(f[2], f[3], w, true);
        h8[(size_t)(n0 + n) * 32 + c] = w;
    }
}

// ---------------- fused GCN layer: 8-lane-group agg -> LDS A-tile -> MFMA ----------------
// (byte-exact the 356-us champion kernel -- do not perturb; see header note)
// 32 nodes per 256-thread block. Lane = (group grp = lane>>3 -> node, chunk cc4 =
// lane&7 -> 16B uint4 of the row). One gather instruction covers 8 node rows.
// Unroll-4 over edges. sIdx window UNIONED with Cs (disjoint phases) -> 16 KB LDS.

__global__ __launch_bounds__(256, 4) void gcn_fused_kernel(const unsigned* __restrict__ h8,
                                                           unsigned* __restrict__ out8,
                                                           unsigned* __restrict__ outb,
                                                           const unsigned* __restrict__ Wb,
                                                           const float* __restrict__ bias,
                                                           const int* __restrict__ rp,
                                                           const int* __restrict__ csr,
                                                           const float* __restrict__ degf,
                                                           int col0fix, int N) {
    __shared__ unsigned Al[32 * 64];     // A tile, swizzled: row r granule gr at Al[(r*16 + (gr^(r&7)))*4]
    __shared__ unsigned CsS[32 * 64];    // C staging; first EW*4 bytes double as sIdx during agg
    int* sIdx = (int*)CsS;
    int t = threadIdx.x;
    int wv = t >> 6, lane = t & 63;
    int grp = lane >> 3;               // node group 0..7 within wave
    int cc4 = lane & 7;                // 16B chunk 0..7
    int n0 = blockIdx.x * 32;
    int g32 = wv * 8 + grp;            // local row 0..31
    int i = n0 + g32;
    const char* hbase = (const char*)h8;
    unsigned c16 = (unsigned)cc4 * 16u;

    int start = 0, end = 0;
    if (i < N) { start = rp[i]; end = rp[i + 1]; }
    int deg = end - start;
    int nEnd = min(n0 + 32, N);
    int s0 = rp[n0];                   // block-uniform
    int e1 = rp[nEnd];

    floatx2 a0 = {0.f, 0.f}, a1 = {0.f, 0.f}, a2 = {0.f, 0.f}, a3 = {0.f, 0.f};
    floatx2 a4 = {0.f, 0.f}, a5 = {0.f, 0.f}, a6 = {0.f, 0.f}, a7 = {0.f, 0.f};
    float dsum = 0.f;

    #define GATH4(ii) (*(const uint4*)(hbase + (((unsigned)(ii) << 7) + c16)))
    #define ACC4(vv) do { \
        a0 += __builtin_amdgcn_cvt_pk_f32_fp8((vv).x, false); \
        a1 += __builtin_amdgcn_cvt_pk_f32_fp8((vv).x, true);  \
        a2 += __builtin_amdgcn_cvt_pk_f32_fp8((vv).y, false); \
        a3 += __builtin_amdgcn_cvt_pk_f32_fp8((vv).y, true);  \
        a4 += __builtin_amdgcn_cvt_pk_f32_fp8((vv).z, false); \
        a5 += __builtin_amdgcn_cvt_pk_f32_fp8((vv).z, true);  \
        a6 += __builtin_amdgcn_cvt_pk_f32_fp8((vv).w, false); \
        a7 += __builtin_amdgcn_cvt_pk_f32_fp8((vv).w, true);  \
    } while (0)

    for (int w0 = s0; w0 < e1; w0 += EW) {
        if (w0 > s0) __syncthreads();   // protect sIdx reuse (uniform cond)
        int wcnt = min(EW, e1 - w0);
        for (int j = t; j < wcnt; j += 256) sIdx[j] = csr[w0 + j];
        __syncthreads();
        int p  = max(start, w0) - w0;
        int pe = min(end, w0 + wcnt) - w0;
        for (; p + 4 <= pe; p += 4) {
            int iA = sIdx[p], iB = sIdx[p + 1], iC = sIdx[p + 2], iD = sIdx[p + 3];
            uint4 vA = GATH4(iA), vB = GATH4(iB), vC = GATH4(iC), vD = GATH4(iD);
            if (col0fix && cc4 == 0)
                dsum += degf[iA] + degf[iB] + degf[iC] + degf[iD];
            ACC4(vA); ACC4(vB); ACC4(vC); ACC4(vD);
        }
        for (; p + 2 <= pe; p += 2) {
            int iA = sIdx[p], iB = sIdx[p + 1];
            uint4 vA = GATH4(iA), vB = GATH4(iB);
            if (col0fix && cc4 == 0) dsum += degf[iA] + degf[iB];
            ACC4(vA); ACC4(vB);
        }
        for (; p < pe; ++p) {
            int iA = sIdx[p];
            uint4 vA = GATH4(iA);
            if (col0fix && cc4 == 0) dsum += degf[iA];
            ACC4(vA);
        }
    }

    if (i < N) {
        float inv;
        if (deg == 0) {                 // keep old h: accumulate own row once
            uint4 v = GATH4(i);
            ACC4(v);
            inv = 1.f;
        } else {
            if (col0fix && cc4 == 0) a0[0] = dsum;   // exact neighbor-deg sum -> logical col 0
            inv = 1.f / (float)deg;
        }
        uint4 r0, r1;
        r0.x = pack_bf2(a0[0] * inv, a0[1] * inv);
        r0.y = pack_bf2(a1[0] * inv, a1[1] * inv);
        r0.z = pack_bf2(a2[0] * inv, a2[1] * inv);
        r0.w = pack_bf2(a3[0] * inv, a3[1] * inv);
        r1.x = pack_bf2(a4[0] * inv, a4[1] * inv);
        r1.y = pack_bf2(a5[0] * inv, a5[1] * inv);
        r1.z = pack_bf2(a6[0] * inv, a6[1] * inv);
        r1.w = pack_bf2(a7[0] * inv, a7[1] * inv);
        int gr0 = 2 * cc4, gr1 = 2 * cc4 + 1;
        *(uint4*)&Al[(g32 * 16 + (gr0 ^ (g32 & 7))) * 4] = r0;
        *(uint4*)&Al[(g32 * 16 + (gr1 ^ (g32 & 7))) * 4] = r1;
    }
    __syncthreads();

    // ---- GEMM phase: wave wv -> rows rh*16..+15, output tiles ot=cq*4..cq*4+3 ----
    {
        int rh = wv & 1, cq = wv >> 1;
        int m = lane & 15, q = lane >> 4;
        int r = rh * 16 + m;           // A row (node) index
        floatx4 acc0 = (floatx4)(0.f), acc1 = (floatx4)(0.f);
        floatx4 acc2 = (floatx4)(0.f), acc3 = (floatx4)(0.f);
        #pragma unroll
        for (int kt = 0; kt < 4; ++kt) {
            short8 af = *(const short8*)&Al[(r * 16 + ((kt * 4 + q) ^ (m & 7))) * 4];
            short8 b0 = *(const short8*)&Wb[((cq * 4 + 0) * 16 + m) * 64 + kt * 16 + q * 4];
            short8 b1 = *(const short8*)&Wb[((cq * 4 + 1) * 16 + m) * 64 + kt * 16 + q * 4];
            short8 b2 = *(const short8*)&Wb[((cq * 4 + 2) * 16 + m) * 64 + kt * 16 + q * 4];
            short8 b3 = *(const short8*)&Wb[((cq * 4 + 3) * 16 + m) * 64 + kt * 16 + q * 4];
            acc0 = __builtin_amdgcn_mfma_f32_16x16x32_bf16(af, b0, acc0, 0, 0, 0);
            acc1 = __builtin_amdgcn_mfma_f32_16x16x32_bf16(af, b1, acc1, 0, 0, 0);
            acc2 = __builtin_amdgcn_mfma_f32_16x16x32_bf16(af, b2, acc2, 0, 0, 0);
            acc3 = __builtin_amdgcn_mfma_f32_16x16x32_bf16(af, b3, acc3, 0, 0, 0);
        }
        float bv0 = bias[(cq * 4 + 0) * 16 + m];
        float bv1 = bias[(cq * 4 + 1) * 16 + m];
        float bv2 = bias[(cq * 4 + 2) * 16 + m];
        float bv3 = bias[(cq * 4 + 3) * 16 + m];
        #pragma unroll
        for (int r4 = 0; r4 < 4; ++r4) {
            int row = rh * 16 + q * 4 + r4;
            float v0 = fmaxf(acc0[r4] + bv0, 0.f);
            float v1 = fmaxf(acc1[r4] + bv1, 0.f);
            float v2 = fmaxf(acc2[r4] + bv2, 0.f);
            float v3 = fmaxf(acc3[r4] + bv3, 0.f);
            if (out8) {
                // phys fp8 bytes m*8 + cq*4 + {0..3} -> one aligned u32
                unsigned pk = __builtin_amdgcn_cvt_pk_fp8_f32(v0, v1, 0, false);
                pk = __builtin_amdgcn_cvt_pk_fp8_f32(v2, v3, pk, true);
                *(unsigned*)((char*)CsS + row * 128 + m * 8 + cq * 4) = pk;
            } else {
                // phys bf16 u32 indices m*4 + cq*2 + {0,1} within row of 64 u32
                CsS[row * 64 + m * 4 + cq * 2 + 0] = pack_bf2(v0, v1);
                CsS[row * 64 + m * 4 + cq * 2 + 1] = pack_bf2(v2, v3);
            }
        }
    }
    __syncthreads();

    // ---- coalesced writeout: 32 rows ----
    {
        int row = t >> 3, gg = t & 7;
        int n = n0 + row;
        if (n < N) {
            if (out8) {
                ((uint4*)out8)[(size_t)n * 8 + gg] =
                    *(const uint4*)((const char*)CsS + row * 128 + gg * 16);
            } else {
                ((uint4*)outb)[(size_t)n * 16 + 2 * gg]     = *(const uint4*)&CsS[row * 64 + 8 * gg];
                ((uint4*)outb)[(size_t)n * 16 + 2 * gg + 1] = *(const uint4*)&CsS[row * 64 + 8 * gg + 4];
            }
        }
    }
    #undef GATH4
    #undef ACC4
}

// ---------------- graph mean-pool + counts: 64-node blocks, 4-way node striping ----------------

__global__ __launch_bounds__(256) void pool_kernel(const unsigned* __restrict__ h,
                                                   const int* __restrict__ gid,
                                                   float* __restrict__ hg,
                                                   float* __restrict__ counts, int N) {
    int c = threadIdx.x & 63;
    int q = threadIdx.x >> 6;
    int n0 = blockIdx.x * 64;
    int nend = min(n0 + 64, N);
    float ax = 0.f, ay = 0.f, cnt = 0.f;
    int cur = -1;
    for (int n = n0 + q; n < nend; n += 4) {
        int g = gid[n];
        if (g != cur) {
            if (cur >= 0) {
                atomicAdd(&hg[cur * HID + 2 * c], ax);
                atomicAdd(&hg[cur * HID + 2 * c + 1], ay);
                if (c == 0) atomicAdd(&counts[cur], cnt);
            }
            ax = ay = cnt = 0.f;
            cur = g;
        }
        unsigned v = h[(size_t)n * 64 + c];
        ax += bf_lo(v); ay += bf_hi(v);
        cnt += 1.f;
    }
    if (cur >= 0) {
        atomicAdd(&hg[cur * HID + 2 * c], ax);
        atomicAdd(&hg[cur * HID + 2 * c + 1], ay);
        if (c == 0) atomicAdd(&counts[cur], cnt);
    }
}

// ---------------- fused classifier head (fp32), one block per graph ----------------

__global__ __launch_bounds__(128) void cls_fused_kernel(const float* __restrict__ hg,
                                                        const float* __restrict__ counts,
                                                        const float* __restrict__ Wc1p,
                                                        const float* __restrict__ Wc1,
                                                        const float* __restrict__ bc1,
                                                        const float* __restrict__ Wc2,
                                                        const float* __restrict__ bc2,
                                                        float* __restrict__ out, int G) {
    __shared__ float x[128];
    __shared__ float y[128];
    __shared__ float red[128];
    int g = blockIdx.x, t = threadIdx.x;
    float inv = 1.f / fmaxf(counts[g], 1.f);
    x[t] = hg[g * HID + t] * inv;
    __syncthreads();
    const float4* wp4 = (const float4*)(Wc1p + t * HID);
    float s = 0.f;
    #pragma unroll
    for (int k4 = 0; k4 < 32; ++k4) {
        float4 w = wp4[k4];
        s += x[k4 * 4] * w.x + x[k4 * 4 + 1] * w.y + x[k4 * 4 + 2] * w.z + x[k4 * 4 + 3] * w.w;
    }
    y[t] = s + bc1[t];
    __syncthreads();
    const float4* w4 = (const float4*)(Wc1 + t * HID);
    float s2 = 0.f;
    #pragma unroll
    for (int k4 = 0; k4 < 32; ++k4) {
        float4 w = w4[k4];
        s2 += y[k4 * 4] * w.x + y[k4 * 4 + 1] * w.y + y[k4 * 4 + 2] * w.z + y[k4 * 4 + 3] * w.w;
    }
    red[t] = (s2 + bc1[t]) * Wc2[t];
    __syncthreads();
    if (t < 64) {
        float r = red[t] + red[t + 64];
        #pragma unroll
        for (int off = 32; off > 0; off >>= 1) r += __shfl_down(r, off);
        if (t == 0) out[g] = r + bc2[0];
    }
}

// ---------------- launch ----------------

extern "C" void kernel_launch(void* const* d_in, const int* in_sizes, int n_in,
                              void* d_out, int out_size, void* d_ws, size_t ws_size,
                              hipStream_t stream) {
    const float* feat = (const float*)d_in[0];
    const int* src    = (const int*)d_in[1];
    const int* dst    = (const int*)d_in[2];
    const int* gid    = (const int*)d_in[3];
    const float* W0  = (const float*)d_in[5];
    const float* b0  = (const float*)d_in[6];
    const float* W1  = (const float*)d_in[7];
    const float* b1  = (const float*)d_in[8];
    const float* W2  = (const float*)d_in[9];
    const float* b2  = (const float*)d_in[10];
    const float* Wc1 = (const float*)d_in[11];
    const float* bc1 = (const float*)d_in[12];
    const float* Wc2 = (const float*)d_in[13];
    const float* bc2 = (const float*)d_in[14];

    const int N = in_sizes[3];
    const int E = in_sizes[1];
    const int G = out_size;
    const int NB = (N + BNODES - 1) >> BSH;

    char* ws = (char*)d_ws;
    size_t off = 0;
    auto alloc = [&](size_t bytes) { void* p = ws + off; off += (bytes + 255) & ~size_t(255); return p; };
    unsigned* h8a    = (unsigned*)alloc((size_t)(N + 1) * 32 * 4);   // fp8 h buffer A (+sentinel row)
    unsigned* h8b    = (unsigned*)alloc((size_t)(N + 1) * 32 * 4);   // fp8 h buffer B (+sentinel row)
    unsigned* hB     = (unsigned*)alloc((size_t)N * 64 * 4);         // bf16 h3 for pool
    float* degf      = (float*)alloc((size_t)(N + 1) * 4);           // exact in-degree (+sentinel 0)
    unsigned* staging = (unsigned*)alloc((size_t)E * 4);             // packed (src<<8)|dst_local
    int* csr         = (int*)alloc((size_t)(E + 64) * 4);
    int* rp          = (int*)alloc((size_t)(N + 1) * 4);
    int* gbucket     = (int*)alloc(512 * 4);
    int* bstart      = (int*)alloc(513 * 4);
    int* gcur        = (int*)alloc(512 * 4);
    unsigned* Wb0    = (unsigned*)alloc(8192 * 4);
    unsigned* Wb1    = (unsigned*)alloc(8192 * 4);
    unsigned* Wb2    = (unsigned*)alloc(8192 * 4);
    float* Wc1p      = (float*)alloc(16384 * 4);
    float* hg        = (float*)alloc((size_t)G * HID * 4);
    float* counts    = (float*)alloc((size_t)G * 4);

    init_kernel<<<96, 256, 0, stream>>>(W0, W1, W2, Wc1, Wb0, Wb1, Wb2, Wc1p,
                                        gbucket, hg, counts, h8a, h8b, G, N);

    int gE = (E + 4095) / 4096;
    bucket_count_kernel<<<gE, 256, 0, stream>>>(dst, gbucket, E, NB);
    bucket_scan_kernel<<<1, 512, 0, stream>>>(gbucket, bstart, gcur, NB, E);
    bucket_scatter_kernel<<<gE, 256, 0, stream>>>(src, dst, gcur, staging, E, NB);
    csr_build_kernel<<<NB, 256, 0, stream>>>(staging, bstart, rp, csr, degf, N, E, NB);

    build_h0_kernel<<<(N + 7) / 8, 256, 0, stream>>>(feat, h8a, N);

    int layer_grid = (N + 31) / 32;
    gcn_fused_kernel<<<layer_grid, 256, 0, stream>>>(h8a, h8b, nullptr, Wb0, b0, rp, csr, degf, 1, N);
    gcn_fused_kernel<<<layer_grid, 256, 0, stream>>>(h8b, h8a, nullptr, Wb1, b1, rp, csr, degf, 0, N);
    gcn_fused_kernel<<<layer_grid, 256, 0, stream>>>(h8a, nullptr, hB, Wb2, b2, rp, csr, degf, 0, N);

    pool_kernel<<<(N + 63) / 64, 256, 0, stream>>>(hB, gid, hg, counts, N);

    cls_fused_kernel<<<G, 128, 0, stream>>>(hg, counts, Wc1p, Wc1, bc1, Wc2, bc2,
                                            (float*)d_out, G);
}

// Round 11
// 349.431 us; speedup vs baseline: 1.3783x; 1.0197x over previous
//
#include <hip/hip_runtime.h>
#include <hip/hip_bf16.h>

#define HID 128
#define NRAW 127
#define BSH 8          // 256 nodes per bucket
#define BNODES 256
#define EW 2048        // LDS-staged csr window (edges), fits in Cs union (8 KB)
#define BCAP 5120      // csr_build LDS edge stage (20 KB); avg 4096/bucket, +16 sigma

// Column permutation: all hidden-state tensors (h8a/h8b, hB, hg) store logical
// column l = ot*16+m at physical position p = m*8+ot; inverse invp(p) = (p&7)*16+(p>>3).
// GEMM weights and the first Wc1 application are k-permuted to match.
//
// prep_kernel fuses three independent launches (init extras + bucket_count +
// build_h0) into disjoint blockIdx ranges: count's LDS-atomic phase overlaps
// h0's HBM-bound read. gbucket is zeroed by hipMemsetAsync beforehand.
//
// CSR: bucketed 2-phase counting sort (R8 showed non-bucketed scatter costs
// 90us via cross-XCD dirty-line bouncing). csr_build stages edges in LDS.
//
// gcn_fused_kernel is byte-exact the 356us champion (R5): uint4 8-lane groups,
// unroll-4, LDS sIdx window unioned with Cs, XOR-swizzled A-tile. Its gather
// phase sits at a per-CU memory-parallelism ceiling (R6/R9 probes null) and
// its codegen is perturbation-fragile (R7) -- do not touch this kernel.

typedef __attribute__((ext_vector_type(8))) short short8;
typedef __attribute__((ext_vector_type(4))) float floatx4;
typedef __attribute__((ext_vector_type(2))) float floatx2;

__device__ inline unsigned pack_bf2(float x, float y) {
    unsigned bx = __float_as_uint(x);
    unsigned by = __float_as_uint(y);
    bx += 0x7fffu + ((bx >> 16) & 1u);   // RNE
    by += 0x7fffu + ((by >> 16) & 1u);
    return (bx >> 16) | (by & 0xffff0000u);
}
__device__ inline float bf_lo(unsigned u) { return __uint_as_float(u << 16); }
__device__ inline float bf_hi(unsigned u) { return __uint_as_float(u & 0xffff0000u); }

// ---------------- prep: bucket_count (blocks<gE) | init extras + build_h0 (rest) ----------------

__global__ __launch_bounds__(256) void prep_kernel(const int* __restrict__ dst,
                                                   int* __restrict__ gbucket,
                                                   const float* __restrict__ feat,
                                                   unsigned* __restrict__ h8a,
                                                   unsigned* __restrict__ h8b,
                                                   const float* __restrict__ W0,
                                                   const float* __restrict__ W1,
                                                   const float* __restrict__ W2,
                                                   const float* __restrict__ Wc1,
                                                   unsigned* __restrict__ O0,
                                                   unsigned* __restrict__ O1,
                                                   unsigned* __restrict__ O2,
                                                   float* __restrict__ Wc1p,
                                                   float* __restrict__ hg,
                                                   float* __restrict__ counts,
                                                   int E, int NB, int gE, int N, int G) {
    __shared__ int hist[512];
    __shared__ float lf[8 * NRAW];
    int t = threadIdx.x;
    int blk = blockIdx.x;
    if (blk < gE) {
        // ---- bucket_count body ----
        for (int b = t; b < NB; b += 256) hist[b] = 0;
        __syncthreads();
        int base = blk * 4096;
        #pragma unroll
        for (int j = 0; j < 16; ++j) {
            int e = base + j * 256 + t;
            if (e < E) atomicAdd(&hist[dst[e] >> BSH], 1);
        }
        __syncthreads();
        for (int b = t; b < NB; b += 256) {
            int v = hist[b];
            if (v) atomicAdd(&gbucket[b], v);
        }
    } else {
        int hb = blk - gE;
        // ---- init extras (ids 0..24575 live in the first 96 h0 blocks) ----
        int id = hb * 256 + t;
        if (id < G * HID) hg[id] = 0.f;
        if (id < G) counts[id] = 0.f;
        if (id < 32) {                       // sentinel zero rows (safety)
            h8a[(size_t)N * 32 + id] = 0u;
            h8b[(size_t)N * 32 + id] = 0u;
        }
        if (id < 16384) {   // Wc1 with permuted k for the first head matmul
            int tt = id >> 7, p = id & 127;
            Wc1p[id] = Wc1[tt * 128 + ((p & 7) * 16 + (p >> 3))];
        }
        if (id < 3 * 8192) {   // GCN weights, bf16, k-permuted
            int sel = id >> 13, l = id & 8191;
            const float* W = sel == 0 ? W0 : (sel == 1 ? W1 : W2);
            unsigned* O = sel == 0 ? O0 : (sel == 1 ? O1 : O2);
            int o = l >> 6, pp = (l & 63) * 2;
            int k0 = (pp & 7) * 16 + (pp >> 3);
            int k1 = ((pp + 1) & 7) * 16 + ((pp + 1) >> 3);
            O[l] = pack_bf2(W[o * 128 + k0], W[o * 128 + k1]);
        }
        // ---- build_h0 body ----
        int n0 = hb * 8;
        int nrows = min(8, N - n0);
        if (nrows > 0) {
            int total = nrows * NRAW;
            for (int j = t; j < total; j += 256) lf[j] = feat[(size_t)n0 * NRAW + j];
            __syncthreads();
            int n = t >> 5, c = t & 31;
            if (n < nrows) {
                const float* fr = lf + n * NRAW;
                int base = c >> 1, hbq = (c & 1) * 4;
                float f[4];
                #pragma unroll
                for (int j = 0; j < 4; ++j) {
                    int l = (hbq + j) * 16 + base;   // logical col at physical byte 4c+j
                    f[j] = (l == 0) ? 0.f : fr[l - 1];
                }
                unsigned w = __builtin_amdgcn_cvt_pk_fp8_f32(f[0], f[1], 0, false);
                w = __builtin_amdgcn_cvt_pk_fp8_f32(f[2], f[3], w, true);
                h8a[(size_t)(n0 + n) * 32 + c] = w;
            }
        }
    }
}

// ---------------- CSR build: bucketed 2-phase counting sort ----------------

__global__ void bucket_scan_kernel(const int* __restrict__ gbucket, int* __restrict__ bstart,
                                   int* __restrict__ gcur, int NB, int E) {
    __shared__ int sm[512];
    int t = threadIdx.x;
    int v = (t < NB) ? gbucket[t] : 0;
    sm[t] = v;
    __syncthreads();
    for (int off = 1; off < 512; off <<= 1) {
        int add = (t >= off) ? sm[t - off] : 0;
        __syncthreads();
        sm[t] += add;
        __syncthreads();
    }
    if (t < NB) {
        int ex = sm[t] - v;
        bstart[t] = ex;
        gcur[t] = ex;
    }
    if (t == 0) bstart[NB] = E;
}

// staging entry: (src << 8) | (dst & 255)  -- 4 B/edge (src < 2^24, local dst 8 bits)
__global__ __launch_bounds__(256) void bucket_scatter_kernel(const int* __restrict__ src,
                                                             const int* __restrict__ dst,
                                                             int* __restrict__ gcur,
                                                             unsigned* __restrict__ staging,
                                                             int E, int NB) {
    __shared__ int hist[512];
    __shared__ int base[512];
    int t = threadIdx.x;
    for (int b = t; b < NB; b += 256) hist[b] = 0;
    __syncthreads();
    int s[16], d[16], r[16];
    int e0 = blockIdx.x * 4096;
    #pragma unroll
    for (int j = 0; j < 16; ++j) {
        int e = e0 + j * 256 + t;
        if (e < E) {
            s[j] = src[e];
            d[j] = dst[e];
            r[j] = atomicAdd(&hist[d[j] >> BSH], 1);
        } else d[j] = -1;
    }
    __syncthreads();
    for (int b = t; b < NB; b += 256) {
        int v = hist[b];
        base[b] = v ? atomicAdd(&gcur[b], v) : 0;
    }
    __syncthreads();
    #pragma unroll
    for (int j = 0; j < 16; ++j) {
        if (d[j] >= 0) {
            int b = d[j] >> BSH;
            staging[base[b] + r[j]] = ((unsigned)s[j] << 8) | ((unsigned)d[j] & 255u);
        }
    }
}

// Single-pass: stage this bucket's edges into LDS (se), histogram + scan +
// place entirely from LDS. Block-uniform fallback to the global 2-pass path
// if the bucket exceeds BCAP (never for Poisson(4096) buckets; safety only).
__global__ __launch_bounds__(256) void csr_build_kernel(const unsigned* __restrict__ staging,
                                                        const int* __restrict__ bstart,
                                                        int* __restrict__ rp, int* __restrict__ csr,
                                                        float* __restrict__ degf,
                                                        int N, int E, int NB) {
    __shared__ int hist[256];
    __shared__ int sm[256];
    __shared__ int excl[256];
    __shared__ int cnt[256];
    __shared__ unsigned se[BCAP];
    int t = threadIdx.x;
    int b = blockIdx.x;
    int nbase = b << BSH;
    int s0 = bstart[b], e1 = bstart[b + 1];
    int cntE = e1 - s0;                // block-uniform
    bool lds = (cntE <= BCAP);
    hist[t] = 0;
    __syncthreads();
    if (lds) {
        for (int i = t; i < cntE; i += 256) {
            unsigned p = staging[s0 + i];
            se[i] = p;
            atomicAdd(&hist[p & (BNODES - 1)], 1);
        }
    } else {
        for (int i = s0 + t; i < e1; i += 256) {
            unsigned p = staging[i];
            atomicAdd(&hist[p & (BNODES - 1)], 1);
        }
    }
    __syncthreads();
    int h = hist[t];
    sm[t] = h;
    __syncthreads();
    for (int off = 1; off < 256; off <<= 1) {
        int add = (t >= off) ? sm[t - off] : 0;
        __syncthreads();
        sm[t] += add;
        __syncthreads();
    }
    excl[t] = sm[t] - h;
    cnt[t] = 0;
    int n = nbase + t;
    if (n < N) {
        rp[n] = s0 + (sm[t] - h);
        degf[n] = (float)h;
    }
    if (b == NB - 1 && t == 0) {
        rp[N] = E;
        degf[N] = 0.f;                     // sentinel degree
    }
    __syncthreads();
    if (lds) {
        for (int i = t; i < cntE; i += 256) {
            unsigned p = se[i];
            int dl = p & (BNODES - 1);
            int pos = s0 + excl[dl] + atomicAdd(&cnt[dl], 1);
            csr[pos] = (int)(p >> 8);
        }
    } else {
        for (int i = s0 + t; i < e1; i += 256) {
            unsigned p = staging[i];
            int dl = p & (BNODES - 1);
            int pos = s0 + excl[dl] + atomicAdd(&cnt[dl], 1);
            csr[pos] = (int)(p >> 8);
        }
    }
}

// ---------------- fused GCN layer: 8-lane-group agg -> LDS A-tile -> MFMA ----------------
// (byte-exact the 356-us champion kernel -- do not perturb; see header note)
// 32 nodes per 256-thread block. Lane = (group grp = lane>>3 -> node, chunk cc4 =
// lane&7 -> 16B uint4 of the row). One gather instruction covers 8 node rows.
// Unroll-4 over edges. sIdx window UNIONED with Cs (disjoint phases) -> 16 KB LDS.

__global__ __launch_bounds__(256, 4) void gcn_fused_kernel(const unsigned* __restrict__ h8,
                                                           unsigned* __restrict__ out8,
                                                           unsigned* __restrict__ outb,
                                                           const unsigned* __restrict__ Wb,
                                                           const float* __restrict__ bias,
                                                           const int* __restrict__ rp,
                                                           const int* __restrict__ csr,
                                                           const float* __restrict__ degf,
                                                           int col0fix, int N) {
    __shared__ unsigned Al[32 * 64];     // A tile, swizzled: row r granule gr at Al[(r*16 + (gr^(r&7)))*4]
    __shared__ unsigned CsS[32 * 64];    // C staging; first EW*4 bytes double as sIdx during agg
    int* sIdx = (int*)CsS;
    int t = threadIdx.x;
    int wv = t >> 6, lane = t & 63;
    int grp = lane >> 3;               // node group 0..7 within wave
    int cc4 = lane & 7;                // 16B chunk 0..7
    int n0 = blockIdx.x * 32;
    int g32 = wv * 8 + grp;            // local row 0..31
    int i = n0 + g32;
    const char* hbase = (const char*)h8;
    unsigned c16 = (unsigned)cc4 * 16u;

    int start = 0, end = 0;
    if (i < N) { start = rp[i]; end = rp[i + 1]; }
    int deg = end - start;
    int nEnd = min(n0 + 32, N);
    int s0 = rp[n0];                   // block-uniform
    int e1 = rp[nEnd];

    floatx2 a0 = {0.f, 0.f}, a1 = {0.f, 0.f}, a2 = {0.f, 0.f}, a3 = {0.f, 0.f};
    floatx2 a4 = {0.f, 0.f}, a5 = {0.f, 0.f}, a6 = {0.f, 0.f}, a7 = {0.f, 0.f};
    float dsum = 0.f;

    #define GATH4(ii) (*(const uint4*)(hbase + (((unsigned)(ii) << 7) + c16)))
    #define ACC4(vv) do { \
        a0 += __builtin_amdgcn_cvt_pk_f32_fp8((vv).x, false); \
        a1 += __builtin_amdgcn_cvt_pk_f32_fp8((vv).x, true);  \
        a2 += __builtin_amdgcn_cvt_pk_f32_fp8((vv).y, false); \
        a3 += __builtin_amdgcn_cvt_pk_f32_fp8((vv).y, true);  \
        a4 += __builtin_amdgcn_cvt_pk_f32_fp8((vv).z, false); \
        a5 += __builtin_amdgcn_cvt_pk_f32_fp8((vv).z, true);  \
        a6 += __builtin_amdgcn_cvt_pk_f32_fp8((vv).w, false); \
        a7 += __builtin_amdgcn_cvt_pk_f32_fp8((vv).w, true);  \
    } while (0)

    for (int w0 = s0; w0 < e1; w0 += EW) {
        if (w0 > s0) __syncthreads();   // protect sIdx reuse (uniform cond)
        int wcnt = min(EW, e1 - w0);
        for (int j = t; j < wcnt; j += 256) sIdx[j] = csr[w0 + j];
        __syncthreads();
        int p  = max(start, w0) - w0;
        int pe = min(end, w0 + wcnt) - w0;
        for (; p + 4 <= pe; p += 4) {
            int iA = sIdx[p], iB = sIdx[p + 1], iC = sIdx[p + 2], iD = sIdx[p + 3];
            uint4 vA = GATH4(iA), vB = GATH4(iB), vC = GATH4(iC), vD = GATH4(iD);
            if (col0fix && cc4 == 0)
                dsum += degf[iA] + degf[iB] + degf[iC] + degf[iD];
            ACC4(vA); ACC4(vB); ACC4(vC); ACC4(vD);
        }
        for (; p + 2 <= pe; p += 2) {
            int iA = sIdx[p], iB = sIdx[p + 1];
            uint4 vA = GATH4(iA), vB = GATH4(iB);
            if (col0fix && cc4 == 0) dsum += degf[iA] + degf[iB];
            ACC4(vA); ACC4(vB);
        }
        for (; p < pe; ++p) {
            int iA = sIdx[p];
            uint4 vA = GATH4(iA);
            if (col0fix && cc4 == 0) dsum += degf[iA];
            ACC4(vA);
        }
    }

    if (i < N) {
        float inv;
        if (deg == 0) {                 // keep old h: accumulate own row once
            uint4 v = GATH4(i);
            ACC4(v);
            inv = 1.f;
        } else {
            if (col0fix && cc4 == 0) a0[0] = dsum;   // exact neighbor-deg sum -> logical col 0
            inv = 1.f / (float)deg;
        }
        uint4 r0, r1;
        r0.x = pack_bf2(a0[0] * inv, a0[1] * inv);
        r0.y = pack_bf2(a1[0] * inv, a1[1] * inv);
        r0.z = pack_bf2(a2[0] * inv, a2[1] * inv);
        r0.w = pack_bf2(a3[0] * inv, a3[1] * inv);
        r1.x = pack_bf2(a4[0] * inv, a4[1] * inv);
        r1.y = pack_bf2(a5[0] * inv, a5[1] * inv);
        r1.z = pack_bf2(a6[0] * inv, a6[1] * inv);
        r1.w = pack_bf2(a7[0] * inv, a7[1] * inv);
        int gr0 = 2 * cc4, gr1 = 2 * cc4 + 1;
        *(uint4*)&Al[(g32 * 16 + (gr0 ^ (g32 & 7))) * 4] = r0;
        *(uint4*)&Al[(g32 * 16 + (gr1 ^ (g32 & 7))) * 4] = r1;
    }
    __syncthreads();

    // ---- GEMM phase: wave wv -> rows rh*16..+15, output tiles ot=cq*4..cq*4+3 ----
    {
        int rh = wv & 1, cq = wv >> 1;
        int m = lane & 15, q = lane >> 4;
        int r = rh * 16 + m;           // A row (node) index
        floatx4 acc0 = (floatx4)(0.f), acc1 = (floatx4)(0.f);
        floatx4 acc2 = (floatx4)(0.f), acc3 = (floatx4)(0.f);
        #pragma unroll
        for (int kt = 0; kt < 4; ++kt) {
            short8 af = *(const short8*)&Al[(r * 16 + ((kt * 4 + q) ^ (m & 7))) * 4];
            short8 b0 = *(const short8*)&Wb[((cq * 4 + 0) * 16 + m) * 64 + kt * 16 + q * 4];
            short8 b1 = *(const short8*)&Wb[((cq * 4 + 1) * 16 + m) * 64 + kt * 16 + q * 4];
            short8 b2 = *(const short8*)&Wb[((cq * 4 + 2) * 16 + m) * 64 + kt * 16 + q * 4];
            short8 b3 = *(const short8*)&Wb[((cq * 4 + 3) * 16 + m) * 64 + kt * 16 + q * 4];
            acc0 = __builtin_amdgcn_mfma_f32_16x16x32_bf16(af, b0, acc0, 0, 0, 0);
            acc1 = __builtin_amdgcn_mfma_f32_16x16x32_bf16(af, b1, acc1, 0, 0, 0);
            acc2 = __builtin_amdgcn_mfma_f32_16x16x32_bf16(af, b2, acc2, 0, 0, 0);
            acc3 = __builtin_amdgcn_mfma_f32_16x16x32_bf16(af, b3, acc3, 0, 0, 0);
        }
        float bv0 = bias[(cq * 4 + 0) * 16 + m];
        float bv1 = bias[(cq * 4 + 1) * 16 + m];
        float bv2 = bias[(cq * 4 + 2) * 16 + m];
        float bv3 = bias[(cq * 4 + 3) * 16 + m];
        #pragma unroll
        for (int r4 = 0; r4 < 4; ++r4) {
            int row = rh * 16 + q * 4 + r4;
            float v0 = fmaxf(acc0[r4] + bv0, 0.f);
            float v1 = fmaxf(acc1[r4] + bv1, 0.f);
            float v2 = fmaxf(acc2[r4] + bv2, 0.f);
            float v3 = fmaxf(acc3[r4] + bv3, 0.f);
            if (out8) {
                // phys fp8 bytes m*8 + cq*4 + {0..3} -> one aligned u32
                unsigned pk = __builtin_amdgcn_cvt_pk_fp8_f32(v0, v1, 0, false);
                pk = __builtin_amdgcn_cvt_pk_fp8_f32(v2, v3, pk, true);
                *(unsigned*)((char*)CsS + row * 128 + m * 8 + cq * 4) = pk;
            } else {
                // phys bf16 u32 indices m*4 + cq*2 + {0,1} within row of 64 u32
                CsS[row * 64 + m * 4 + cq * 2 + 0] = pack_bf2(v0, v1);
                CsS[row * 64 + m * 4 + cq * 2 + 1] = pack_bf2(v2, v3);
            }
        }
    }
    __syncthreads();

    // ---- coalesced writeout: 32 rows ----
    {
        int row = t >> 3, gg = t & 7;
        int n = n0 + row;
        if (n < N) {
            if (out8) {
                ((uint4*)out8)[(size_t)n * 8 + gg] =
                    *(const uint4*)((const char*)CsS + row * 128 + gg * 16);
            } else {
                ((uint4*)outb)[(size_t)n * 16 + 2 * gg]     = *(const uint4*)&CsS[row * 64 + 8 * gg];
                ((uint4*)outb)[(size_t)n * 16 + 2 * gg + 1] = *(const uint4*)&CsS[row * 64 + 8 * gg + 4];
            }
        }
    }
    #undef GATH4
    #undef ACC4
}

// ---------------- graph mean-pool + counts: 64-node blocks, 4-way node striping ----------------

__global__ __launch_bounds__(256) void pool_kernel(const unsigned* __restrict__ h,
                                                   const int* __restrict__ gid,
                                                   float* __restrict__ hg,
                                                   float* __restrict__ counts, int N) {
    int c = threadIdx.x & 63;
    int q = threadIdx.x >> 6;
    int n0 = blockIdx.x * 64;
    int nend = min(n0 + 64, N);
    float ax = 0.f, ay = 0.f, cnt = 0.f;
    int cur = -1;
    for (int n = n0 + q; n < nend; n += 4) {
        int g = gid[n];
        if (g != cur) {
            if (cur >= 0) {
                atomicAdd(&hg[cur * HID + 2 * c], ax);
                atomicAdd(&hg[cur * HID + 2 * c + 1], ay);
                if (c == 0) atomicAdd(&counts[cur], cnt);
            }
            ax = ay = cnt = 0.f;
            cur = g;
        }
        unsigned v = h[(size_t)n * 64 + c];
        ax += bf_lo(v); ay += bf_hi(v);
        cnt += 1.f;
    }
    if (cur >= 0) {
        atomicAdd(&hg[cur * HID + 2 * c], ax);
        atomicAdd(&hg[cur * HID + 2 * c + 1], ay);
        if (c == 0) atomicAdd(&counts[cur], cnt);
    }
}

// ---------------- fused classifier head (fp32), one block per graph ----------------

__global__ __launch_bounds__(128) void cls_fused_kernel(const float* __restrict__ hg,
                                                        const float* __restrict__ counts,
                                                        const float* __restrict__ Wc1p,
                                                        const float* __restrict__ Wc1,
                                                        const float* __restrict__ bc1,
                                                        const float* __restrict__ Wc2,
                                                        const float* __restrict__ bc2,
                                                        float* __restrict__ out, int G) {
    __shared__ float x[128];
    __shared__ float y[128];
    __shared__ float red[128];
    int g = blockIdx.x, t = threadIdx.x;
    float inv = 1.f / fmaxf(counts[g], 1.f);
    x[t] = hg[g * HID + t] * inv;
    __syncthreads();
    const float4* wp4 = (const float4*)(Wc1p + t * HID);
    float s = 0.f;
    #pragma unroll
    for (int k4 = 0; k4 < 32; ++k4) {
        float4 w = wp4[k4];
        s += x[k4 * 4] * w.x + x[k4 * 4 + 1] * w.y + x[k4 * 4 + 2] * w.z + x[k4 * 4 + 3] * w.w;
    }
    y[t] = s + bc1[t];
    __syncthreads();
    const float4* w4 = (const float4*)(Wc1 + t * HID);
    float s2 = 0.f;
    #pragma unroll
    for (int k4 = 0; k4 < 32; ++k4) {
        float4 w = w4[k4];
        s2 += y[k4 * 4] * w.x + y[k4 * 4 + 1] * w.y + y[k4 * 4 + 2] * w.z + y[k4 * 4 + 3] * w.w;
    }
    red[t] = (s2 + bc1[t]) * Wc2[t];
    __syncthreads();
    if (t < 64) {
        float r = red[t] + red[t + 64];
        #pragma unroll
        for (int off = 32; off > 0; off >>= 1) r += __shfl_down(r, off);
        if (t == 0) out[g] = r + bc2[0];
    }
}

// ---------------- launch ----------------

extern "C" void kernel_launch(void* const* d_in, const int* in_sizes, int n_in,
                              void* d_out, int out_size, void* d_ws, size_t ws_size,
                              hipStream_t stream) {
    const float* feat = (const float*)d_in[0];
    const int* src    = (const int*)d_in[1];
    const int* dst    = (const int*)d_in[2];
    const int* gid    = (const int*)d_in[3];
    const float* W0  = (const float*)d_in[5];
    const float* b0  = (const float*)d_in[6];
    const float* W1  = (const float*)d_in[7];
    const float* b1  = (const float*)d_in[8];
    const float* W2  = (const float*)d_in[9];
    const float* b2  = (const float*)d_in[10];
    const float* Wc1 = (const float*)d_in[11];
    const float* bc1 = (const float*)d_in[12];
    const float* Wc2 = (const float*)d_in[13];
    const float* bc2 = (const float*)d_in[14];

    const int N = in_sizes[3];
    const int E = in_sizes[1];
    const int G = out_size;
    const int NB = (N + BNODES - 1) >> BSH;

    char* ws = (char*)d_ws;
    size_t off = 0;
    auto alloc = [&](size_t bytes) { void* p = ws + off; off += (bytes + 255) & ~size_t(255); return p; };
    unsigned* h8a    = (unsigned*)alloc((size_t)(N + 1) * 32 * 4);   // fp8 h buffer A (+sentinel row)
    unsigned* h8b    = (unsigned*)alloc((size_t)(N + 1) * 32 * 4);   // fp8 h buffer B (+sentinel row)
    unsigned* hB     = (unsigned*)alloc((size_t)N * 64 * 4);         // bf16 h3 for pool
    float* degf      = (float*)alloc((size_t)(N + 1) * 4);           // exact in-degree (+sentinel 0)
    unsigned* staging = (unsigned*)alloc((size_t)E * 4);             // packed (src<<8)|dst_local
    int* csr         = (int*)alloc((size_t)(E + 64) * 4);
    int* rp          = (int*)alloc((size_t)(N + 1) * 4);
    int* gbucket     = (int*)alloc(512 * 4);
    int* bstart      = (int*)alloc(513 * 4);
    int* gcur        = (int*)alloc(512 * 4);
    unsigned* Wb0    = (unsigned*)alloc(8192 * 4);
    unsigned* Wb1    = (unsigned*)alloc(8192 * 4);
    unsigned* Wb2    = (unsigned*)alloc(8192 * 4);
    float* Wc1p      = (float*)alloc(16384 * 4);
    float* hg        = (float*)alloc((size_t)G * HID * 4);
    float* counts    = (float*)alloc((size_t)G * 4);

    hipMemsetAsync(gbucket, 0, 512 * 4, stream);

    int gE = (E + 4095) / 4096;
    int hE = (N + 7) / 8;
    prep_kernel<<<gE + hE, 256, 0, stream>>>(dst, gbucket, feat, h8a, h8b,
                                             W0, W1, W2, Wc1, Wb0, Wb1, Wb2, Wc1p,
                                             hg, counts, E, NB, gE, N, G);

    bucket_scan_kernel<<<1, 512, 0, stream>>>(gbucket, bstart, gcur, NB, E);
    bucket_scatter_kernel<<<gE, 256, 0, stream>>>(src, dst, gcur, staging, E, NB);
    csr_build_kernel<<<NB, 256, 0, stream>>>(staging, bstart, rp, csr, degf, N, E, NB);

    int layer_grid = (N + 31) / 32;
    gcn_fused_kernel<<<layer_grid, 256, 0, stream>>>(h8a, h8b, nullptr, Wb0, b0, rp, csr, degf, 1, N);
    gcn_fused_kernel<<<layer_grid, 256, 0, stream>>>(h8b, h8a, nullptr, Wb1, b1, rp, csr, degf, 0, N);
    gcn_fused_kernel<<<layer_grid, 256, 0, stream>>>(h8a, nullptr, hB, Wb2, b2, rp, csr, degf, 0, N);

    pool_kernel<<<(N + 63) / 64, 256, 0, stream>>>(hB, gid, hg, counts, N);

    cls_fused_kernel<<<G, 128, 0, stream>>>(hg, counts, Wc1p, Wc1, bc1, Wc2, bc2,
                                            (float*)d_out, G);
}